// Round 6
// baseline (1415.303 us; speedup 1.0000x reference)
//
#include <hip/hip_runtime.h>
#include <hip/hip_fp16.h>

// ---------------------------------------------------------------------------
// Problem constants
//   S=512 tokens, WD=300, TD=100, CE=20, CH=20, H=512, LAB=50, MAXW=16
// Outputs: arc_scores (512x512) | label_scores (50x512) | char_embeds (20x512)
// ---------------------------------------------------------------------------

static __device__ __forceinline__ float sigm(float x) { return 1.f / (1.f + __expf(-x)); }
static __device__ __forceinline__ float ftanh(float x) {
    x = fminf(15.f, fmaxf(-15.f, x));
    float e = __expf(2.f * x);
    return (e - 1.f) / (e + 1.f);
}

typedef _Float16 h2_t __attribute__((ext_vector_type(2)));
typedef _Float16 h8_t __attribute__((ext_vector_type(8)));
typedef float f4_t __attribute__((ext_vector_type(4)));
union U32H2 { unsigned u; h2_t h; unsigned short s[2]; };

static __device__ __forceinline__ float dot2f(unsigned wa, unsigned hb, float c) {
#if __has_builtin(__builtin_amdgcn_fdot2)
    U32H2 a, b; a.u = wa; b.u = hb;
    return __builtin_amdgcn_fdot2(a.h, b.h, c, false);
#else
    U32H2 a, b; a.u = wa; b.u = hb;
    return c + (float)a.h[0] * (float)b.h[0] + (float)a.h[1] * (float)b.h[1];
#endif
}
static __device__ __forceinline__ unsigned short f2h16(float x) {
    return __half_as_ushort(__float2half(x));
}

// ---------------------------------------------------------------------------
// h-queue primitives: agent-scope relaxed atomics. PROVEN (r0/r3, passes
// across graph iterations with the hipMemsetAsync re-zero). The sc0 fast path
// stays shelved (r1/r2/r4 hang family). R5's bundled micro-opts
// (launch_bounds(256,1), shfl pre-reduce, store reorder) are also withheld:
// r5 failed opaquely and this round isolates a single safe delta (label_mfma)
// on the r3-passing baseline for attribution.
// ---------------------------------------------------------------------------
static __device__ __forceinline__ unsigned long long hq_ld(const unsigned long long* p) {
    return __hip_atomic_load(p, __ATOMIC_RELAXED, __HIP_MEMORY_SCOPE_AGENT);
}
static __device__ __forceinline__ void hq_st(unsigned long long* p, unsigned long long v) {
    __hip_atomic_store(p, v, __ATOMIC_RELAXED, __HIP_MEMORY_SCOPE_AGENT);
}

// ---------------------------------------------------------------------------
// Recurrent biLSTM core — round-0/3 body VERBATIM (measured 950us):
// per-thread single-qword poll with embedded step tags, intra-wave shfl
// h-distribution, one barrier, LDS partial-reduce ping-pong, 32-lane gate tail.
// ---------------------------------------------------------------------------
static __device__ void lstm_core(int dir, int s, int tid,
                                 const float* __restrict__ Whh,
                                 const float* __restrict__ xp,
                                 _Float16* __restrict__ lstmh,
                                 unsigned long long* __restrict__ hq,
                                 float* __restrict__ red /* 2*1024 floats LDS */) {
    int lane = tid & 63;
    int g = tid & 31, p = tid >> 5;

    unsigned Wreg[4][32];
#pragma unroll
    for (int q = 0; q < 4; ++q) {
        int gr = q * 512 + s * 32 + g;
        const float* wrow = Whh + (size_t)gr * 512 + p * 64;
#pragma unroll
        for (int u = 0; u < 32; ++u) {
            unsigned lo = f2h16(wrow[2 * u]);
            unsigned hi = f2h16(wrow[2 * u + 1]);
            Wreg[q][u] = lo | (hi << 16);
        }
    }

    float c = 0.f;
    unsigned long long* hbase = hq + dir * 512;
    int qidx = tid;

    for (int t = 0; t < 512; ++t) {
        float x0 = 0.f, x1 = 0.f, x2 = 0.f, x3 = 0.f;
        if (tid < 32) {
            const float* x = xp + (size_t)t * 2048;
            int col = s * 32 + tid;
            x0 = x[col]; x1 = x[512 + col]; x2 = x[1024 + col]; x3 = x[1536 + col];
        }

        unsigned long long* hin = hbase + (t & 1) * 256;
        unsigned tag = (unsigned)t & 0xffffu;
        unsigned long long v = hq_ld(hin + qidx);
        while ((((unsigned)(v >> 16)) & 0xffffu) != tag || ((unsigned)(v >> 48)) != tag)
            v = hq_ld(hin + qidx);
        unsigned hw = (unsigned)(v & 0xffffu) | (((unsigned)((v >> 32) & 0xffffu)) << 16);

        float a0 = 0.f, a1 = 0.f, a2 = 0.f, a3 = 0.f;
        int half_base = lane & 32;
#pragma unroll
        for (int u = 0; u < 32; ++u) {
            unsigned hwu = (unsigned)__shfl((int)hw, half_base + u);
            a0 = dot2f(Wreg[0][u], hwu, a0);
            a1 = dot2f(Wreg[1][u], hwu, a1);
            a2 = dot2f(Wreg[2][u], hwu, a2);
            a3 = dot2f(Wreg[3][u], hwu, a3);
        }
        float* r = red + (t & 1) * 1024 + p * 128 + g * 4;
        r[0] = a0; r[1] = a1; r[2] = a2; r[3] = a3;
        __syncthreads();

        if (tid < 32) {
            float z0 = 0.f, z1 = 0.f, z2 = 0.f, z3 = 0.f;
            const float* rb = red + (t & 1) * 1024;
#pragma unroll
            for (int pp = 0; pp < 8; ++pp) {
                const float* rr = rb + pp * 128 + tid * 4;
                z0 += rr[0]; z1 += rr[1]; z2 += rr[2]; z3 += rr[3];
            }
            z0 += x0; z1 += x1; z2 += x2; z3 += x3;
            c = sigm(z1) * c + sigm(z0) * ftanh(z2);
            float hn = sigm(z3) * ftanh(c);
            int col = s * 32 + tid;
            int row = dir ? (511 - t) : t;
            lstmh[(size_t)row * 1024 + dir * 512 + col] = (_Float16)hn;

            unsigned tw = (unsigned)f2h16(hn) | (((unsigned)(t + 1) & 0xffffu) << 16);
            unsigned other = (unsigned)__shfl_down((int)tw, 1);
            if ((tid & 1) == 0) {
                unsigned long long qv = (unsigned long long)tw |
                                        ((unsigned long long)other << 32);
                hq_st(hbase + ((t + 1) & 1) * 256 + (col >> 1), qv);
            }
        }
    }
}

// ---------------------------------------------------------------------------
// xproj (fp32 tile GEMM) with FUSED embedding gather:
//   A[row,k] = k<300 ? word_emb[sentence[tok]*300+k] : tag_emb[tags[tok]*100+k-300]
//   C = A @ W^T + b, M=512, N=2048, K=400; z=1 reverses token order (backward).
// Only true prerequisite of the LSTM -> runs as its own kernel up front.
// ---------------------------------------------------------------------------
__global__ __launch_bounds__(256) void xproj_k(
    const int* __restrict__ sentence, const int* __restrict__ tags,
    const float* __restrict__ word_emb, const float* __restrict__ tag_emb,
    const float* __restrict__ Wf, const float* __restrict__ bf, float* __restrict__ Cf,
    const float* __restrict__ Wb, const float* __restrict__ bb, float* __restrict__ Cb) {
    __shared__ float smemf[2 * 16 * 65];
    typedef float Row65[65];
    Row65* As = (Row65*)smemf;
    Row65* Bs = (Row65*)(smemf + 16 * 65);
    int idx = blockIdx.x;
    int z = idx >> 8, rem = idx & 255;
    int bn = (rem & 31) * 64, bm = (rem >> 5) * 64;
    const float* W = z ? Wb : Wf;
    const float* bias = z ? bb : bf;
    float* C = z ? Cb : Cf;
    int tx = threadIdx.x & 15, ty = threadIdx.x >> 4;
    float acc[4][4] = {};
    for (int k0 = 0; k0 < 400; k0 += 16) {
#pragma unroll
        for (int i = 0; i < 4; ++i) {
            int e = threadIdx.x + i * 256;
            int m = e >> 4, kk = e & 15;
            int row = bm + m; if (z) row = 511 - row;
            int k = k0 + kk;
            float av = (k < 300) ? word_emb[(size_t)sentence[row] * 300 + k]
                                 : tag_emb[(size_t)tags[row] * 100 + (k - 300)];
            As[kk][m] = av;
            Bs[kk][m] = W[(size_t)(bn + m) * 400 + k];
        }
        __syncthreads();
#pragma unroll
        for (int kk = 0; kk < 16; ++kk) {
            float a0 = As[kk][ty * 4 + 0], a1 = As[kk][ty * 4 + 1];
            float a2 = As[kk][ty * 4 + 2], a3 = As[kk][ty * 4 + 3];
            float b0 = Bs[kk][tx * 4 + 0], b1 = Bs[kk][tx * 4 + 1];
            float b2 = Bs[kk][tx * 4 + 2], b3 = Bs[kk][tx * 4 + 3];
            acc[0][0] += a0 * b0; acc[0][1] += a0 * b1; acc[0][2] += a0 * b2; acc[0][3] += a0 * b3;
            acc[1][0] += a1 * b0; acc[1][1] += a1 * b1; acc[1][2] += a1 * b2; acc[1][3] += a1 * b3;
            acc[2][0] += a2 * b0; acc[2][1] += a2 * b1; acc[2][2] += a2 * b2; acc[2][3] += a2 * b3;
            acc[3][0] += a3 * b0; acc[3][1] += a3 * b1; acc[3][2] += a3 * b2; acc[3][3] += a3 * b3;
        }
        __syncthreads();
    }
#pragma unroll
    for (int i = 0; i < 4; ++i) {
#pragma unroll
        for (int j = 0; j < 4; ++j) {
            int n = bn + tx * 4 + j;
            C[(size_t)(bm + ty * 4 + i) * 2048 + n] = acc[i][j] + bias[n];
        }
    }
}

// ---------------------------------------------------------------------------
// FUSED kernel (r3 structure VERBATIM): blocks [0,32) carry the biLSTM with
// the proven agent-scope exchange; all remaining blocks do the
// lstm-independent prep on the ~224 CUs that previously idled:
//   [   0,  32) biLSTM (dir = bid>>4, s = bid&15)
//   [  32, 544) char LSTM + gram attention (512)
//   [ 544,1568) hconv: 4 head weight mats fp32->fp16 (1024)
//   [1568,2080) warc conv fp32[512][513] -> fp16[512][544] (512)
//   [2080,6130) bconv: biaff_label_W -> fp16 [l][k][h] (4050)
// ---------------------------------------------------------------------------
__global__ __launch_bounds__(256) void fused_k(
    const float* __restrict__ W_hh_f, const float* __restrict__ W_hh_b,
    const float* __restrict__ xpf, const float* __restrict__ xpb,
    _Float16* __restrict__ lstmh, unsigned long long* __restrict__ hq,
    const float* __restrict__ BW, _Float16* __restrict__ Bh,
    const int* __restrict__ chars, const int* __restrict__ char_lengths,
    const float* __restrict__ char_emb, const float* __restrict__ att_W,
    const float* __restrict__ att_b, const float* __restrict__ cW_ih,
    const float* __restrict__ cW_hh, const float* __restrict__ cb,
    float* __restrict__ out2,
    const float* __restrict__ Warc, _Float16* __restrict__ W16arc,
    const float* __restrict__ hw0, const float* __restrict__ hw1,
    const float* __restrict__ hw2, const float* __restrict__ hw3,
    _Float16* __restrict__ Wh16) {
    __shared__ __align__(16) unsigned char smem[16384];
    int bid = blockIdx.x;
    int tid = threadIdx.x;

    if (bid < 32) {
        // ---------------- biLSTM ----------------
        int dir = bid >> 4, s = bid & 15;
        const float* Whh = dir ? W_hh_b : W_hh_f;
        const float* xp = dir ? xpb : xpf;
        lstm_core(dir, s, tid, Whh, xp, lstmh, hq, (float*)smem);
    } else if (bid < 544) {
        // ---------------- char LSTM + gram attention ----------------
        float* Wih = (float*)smem;
        float* Whh2 = Wih + 1600;
        float* cbs = Whh2 + 1600;
        float* attsh = cbs + 80;
        float* xsh = attsh + 20;
        float* hsh = xsh + 20;
        float* prodsh = hsh + 20;
        int wd = bid - 32;
        for (int i = tid; i < 1600; i += 256) { Wih[i] = cW_ih[i]; Whh2[i] = cW_hh[i]; }
        for (int i = tid; i < 80; i += 256) cbs[i] = cb[i];
        if (tid < 20) { attsh[tid] = att_W[tid]; hsh[tid] = 0.f; }
        __syncthreads();

        int L = char_lengths[wd];
        float c = 0.f, accj = 0.f;
        for (int t = 0; t < 16; ++t) {
            if (tid < 20) xsh[tid] = char_emb[(size_t)chars[wd * 16 + t] * 20 + tid];
            __syncthreads();
            float hn = 0.f;
            if (tid < 20) {
                float z[4];
#pragma unroll
                for (int q = 0; q < 4; ++q) {
                    int rr = q * 20 + tid;
                    float sacc = cbs[rr];
                    for (int d = 0; d < 20; ++d)
                        sacc += Wih[rr * 20 + d] * xsh[d] + Whh2[rr * 20 + d] * hsh[d];
                    z[q] = sacc;
                }
                c = sigm(z[1]) * c + sigm(z[0]) * ftanh(z[2]);
                hn = sigm(z[3]) * ftanh(c);
            }
            __syncthreads();
            if (tid < 20) { hsh[tid] = hn; prodsh[tid] = hn * attsh[tid]; }
            __syncthreads();
            if (tid < 20 && t < L) {
                float st = 0.f;
                for (int k = 0; k < 20; ++k) st += prodsh[k];
                accj += hn * st;
            }
            __syncthreads();
        }
        if (tid < 20) out2[tid * 512 + wd] = accj + att_b[0];
    } else if (bid < 1568) {
        // ---------------- hconv: 4 head weight matrices fp32 -> fp16 --------
        size_t e0 = ((size_t)(bid - 544) * 256 + tid) * 8;
        int mat = (int)(e0 >> 19);
        size_t off = e0 & 524287;
        const float* src = (mat == 0 ? hw0 : mat == 1 ? hw1 : mat == 2 ? hw2 : hw3) + off;
        float4 f0 = ((const float4*)src)[0];
        float4 f1 = ((const float4*)src)[1];
        __align__(16) _Float16 hv[8];
        hv[0] = (_Float16)f0.x; hv[1] = (_Float16)f0.y;
        hv[2] = (_Float16)f0.z; hv[3] = (_Float16)f0.w;
        hv[4] = (_Float16)f1.x; hv[5] = (_Float16)f1.y;
        hv[6] = (_Float16)f1.z; hv[7] = (_Float16)f1.w;
        *(uint4*)(Wh16 + e0) = *(const uint4*)hv;
    } else if (bid < 2080) {
        // ---------------- warc conv: [512][513] fp32 -> [512][544] fp16 -----
        int t = bid - 1568;
        for (int j = tid; j < 544; j += 256)
            W16arc[(size_t)t * 544 + j] = (_Float16)((j < 513) ? Warc[(size_t)t * 513 + j] : 0.f);
    } else {
        // ---------------- bconv ----------------
        typedef _Float16 TsRow[68];
        TsRow* Ts = (TsRow*)smem;
        int b2 = bid - 2080;
        int lb = b2 / 81, rem = b2 % 81;
        int h0 = (rem % 9) * 64, k0 = (rem / 9) * 64;
        const float* Bl = BW + (size_t)lb * 513 * 513;
        _Float16* BhL = Bh + (size_t)lb * 576 * 544;
        int tr = tid >> 4, tc = tid & 15;
#pragma unroll
        for (int i = 0; i < 4; ++i) {
            int hl = tr + i * 16;
            int h = h0 + hl;
#pragma unroll
            for (int j = 0; j < 4; ++j) {
                int k = k0 + tc * 4 + j;
                float v = (h < 513 && k < 513) ? Bl[(size_t)h * 513 + k] : 0.f;
                Ts[hl][tc * 4 + j] = (_Float16)v;
            }
        }
        __syncthreads();
        int cr = tid >> 2, hb = (tid & 3) * 16;
        int hg = h0 + hb;
        if (hg < 544) {
            __align__(16) _Float16 tmp[16];
#pragma unroll
            for (int j = 0; j < 16; ++j) tmp[j] = Ts[hb + j][cr];
            uint4* dst = (uint4*)(BhL + (size_t)(k0 + cr) * 544 + hg);
            dst[0] = ((const uint4*)tmp)[0];
            dst[1] = ((const uint4*)tmp)[1];
        }
    }
}

// ---------------------------------------------------------------------------
// Heads MFMA: z[hd] = relu(lstmh @ Wh16[hd]^T + bias[hd]), M=N=512, K=1024.
// Outputs: hd0 -> AD16 fp16[512][512]; hd1 -> AH16 fp16[512][544] (+ones col);
//          hd2 -> LD fp32[512][512];   hd3 -> LH16 fp16[512][544] (+ones col)
// ---------------------------------------------------------------------------
__global__ __launch_bounds__(256) void heads_mfma(
    const _Float16* __restrict__ A, const _Float16* __restrict__ Wh,
    const float* __restrict__ b0, const float* __restrict__ b1,
    const float* __restrict__ b2, const float* __restrict__ b3,
    _Float16* __restrict__ AD16, _Float16* __restrict__ AH16,
    float* __restrict__ LD, _Float16* __restrict__ LH16) {
    __shared__ _Float16 As[64][40];
    __shared__ _Float16 Bs[64][40];
    int hd = blockIdx.z;
    int m0 = blockIdx.y * 64, n0 = blockIdx.x * 64;
    const _Float16* Bp = Wh + (size_t)hd * 512 * 1024;
    const float* bias = (hd == 0) ? b0 : (hd == 1) ? b1 : (hd == 2) ? b2 : b3;
    int tid = threadIdx.x;
    int w = tid >> 6, lane = tid & 63, m = lane & 15, q = lane >> 4;
    int srow = tid >> 2, scol = (tid & 3) * 8;

    f4_t acc[4];
#pragma unroll
    for (int cc = 0; cc < 4; ++cc) acc[cc] = 0;

    for (int k0 = 0; k0 < 1024; k0 += 32) {
        uint4 ad = *(const uint4*)(A + (size_t)(m0 + srow) * 1024 + k0 + scol);
        uint4 bd = *(const uint4*)(Bp + (size_t)(n0 + srow) * 1024 + k0 + scol);
        __syncthreads();
        *(uint4*)(&As[srow][scol]) = ad;
        *(uint4*)(&Bs[srow][scol]) = bd;
        __syncthreads();
        h8_t a  = *(const h8_t*)(&As[w * 16 + m][q * 8]);
        h8_t bb0 = *(const h8_t*)(&Bs[ 0 + m][q * 8]);
        h8_t bb1 = *(const h8_t*)(&Bs[16 + m][q * 8]);
        h8_t bb2 = *(const h8_t*)(&Bs[32 + m][q * 8]);
        h8_t bb3 = *(const h8_t*)(&Bs[48 + m][q * 8]);
        acc[0] = __builtin_amdgcn_mfma_f32_16x16x32_f16(a, bb0, acc[0], 0, 0, 0);
        acc[1] = __builtin_amdgcn_mfma_f32_16x16x32_f16(a, bb1, acc[1], 0, 0, 0);
        acc[2] = __builtin_amdgcn_mfma_f32_16x16x32_f16(a, bb2, acc[2], 0, 0, 0);
        acc[3] = __builtin_amdgcn_mfma_f32_16x16x32_f16(a, bb3, acc[3], 0, 0, 0);
    }
#pragma unroll
    for (int r = 0; r < 4; ++r) {
        int row = m0 + w * 16 + q * 4 + r;
#pragma unroll
        for (int cc = 0; cc < 4; ++cc) {
            int ncol = n0 + cc * 16 + m;
            float v = fmaxf(acc[cc][r] + bias[ncol], 0.f);
            if (hd == 2)      LD[(size_t)row * 512 + ncol] = v;
            else if (hd == 0) AD16[(size_t)row * 512 + ncol] = (_Float16)v;
            else {
                _Float16* dst = (hd == 1) ? AH16 : LH16;
                dst[(size_t)row * 544 + ncol] = (_Float16)v;
            }
        }
    }
    // ones + zero-pad columns (512..543) for the 544-stride fp16 heads
    if ((hd == 1 || hd == 3) && blockIdx.x == 7 && tid < 64) {
        _Float16* dst = (hd == 1) ? AH16 : LH16;
        int row = m0 + tid;
        dst[(size_t)row * 544 + 512] = (_Float16)1.f;
        for (int j = 513; j < 544; ++j) dst[(size_t)row * 544 + j] = (_Float16)0.f;
    }
}

// ---------------------------------------------------------------------------
// uv2: Uh[t] = LH16[best_arcs[t]] (fp16 row copy, 544), V[t] = [LD[t],1,pad0]
// ---------------------------------------------------------------------------
__global__ void uv2_k(const int* __restrict__ best_arcs,
                      const _Float16* __restrict__ LH16, const float* __restrict__ LD,
                      _Float16* __restrict__ Uh, float* __restrict__ V) {
    int t = blockIdx.x;
    int ba = best_arcs[t];
    const unsigned* src = (const unsigned*)(LH16 + (size_t)ba * 544);
    unsigned* dst = (unsigned*)(Uh + (size_t)t * 544);
    for (int j = threadIdx.x; j < 272; j += blockDim.x) dst[j] = src[j];
    for (int j = threadIdx.x; j < 516; j += blockDim.x)
        V[t * 516 + j] = (j < 512) ? LD[(size_t)t * 512 + j] : (j == 512 ? 1.f : 0.f);
}

// ---------------------------------------------------------------------------
// Generic fp16 MFMA GEMM: C[64x64 tile] = A[M,K]@B[N,K]^T, ldc=512.
// C16 != null -> fp16 out; else fp32 out to C32.
// ---------------------------------------------------------------------------
__global__ __launch_bounds__(256) void gemm16_mfma(
    const _Float16* __restrict__ A, int lda,
    const _Float16* __restrict__ B, int ldb, int K,
    _Float16* __restrict__ C16, float* __restrict__ C32) {
    __shared__ _Float16 As[64][40];
    __shared__ _Float16 Bs[64][40];
    int m0 = blockIdx.y * 64, n0 = blockIdx.x * 64;
    int tid = threadIdx.x;
    int w = tid >> 6, lane = tid & 63, m = lane & 15, q = lane >> 4;
    int srow = tid >> 2, scol = (tid & 3) * 8;

    f4_t acc[4];
#pragma unroll
    for (int cc = 0; cc < 4; ++cc) acc[cc] = 0;

    for (int k0 = 0; k0 < K; k0 += 32) {
        uint4 ad = *(const uint4*)(A + (size_t)(m0 + srow) * lda + k0 + scol);
        uint4 bd = *(const uint4*)(B + (size_t)(n0 + srow) * ldb + k0 + scol);
        __syncthreads();
        *(uint4*)(&As[srow][scol]) = ad;
        *(uint4*)(&Bs[srow][scol]) = bd;
        __syncthreads();
        h8_t a  = *(const h8_t*)(&As[w * 16 + m][q * 8]);
        h8_t b0 = *(const h8_t*)(&Bs[ 0 + m][q * 8]);
        h8_t b1 = *(const h8_t*)(&Bs[16 + m][q * 8]);
        h8_t b2 = *(const h8_t*)(&Bs[32 + m][q * 8]);
        h8_t b3 = *(const h8_t*)(&Bs[48 + m][q * 8]);
        acc[0] = __builtin_amdgcn_mfma_f32_16x16x32_f16(a, b0, acc[0], 0, 0, 0);
        acc[1] = __builtin_amdgcn_mfma_f32_16x16x32_f16(a, b1, acc[1], 0, 0, 0);
        acc[2] = __builtin_amdgcn_mfma_f32_16x16x32_f16(a, b2, acc[2], 0, 0, 0);
        acc[3] = __builtin_amdgcn_mfma_f32_16x16x32_f16(a, b3, acc[3], 0, 0, 0);
    }
#pragma unroll
    for (int r = 0; r < 4; ++r) {
        int row = m0 + w * 16 + q * 4 + r;
#pragma unroll
        for (int cc = 0; cc < 4; ++cc) {
            int ncol = n0 + cc * 16 + m;
            if (C16) C16[(size_t)row * 512 + ncol] = (_Float16)acc[cc][r];
            else     C32[(size_t)row * 512 + ncol] = acc[cc][r];
        }
    }
}

// ---------------------------------------------------------------------------
// MFMA label biaffine, K-merged (atomic-free) — THE single delta vs r3:
//   sel[l,t] = sum_k (U[t] @ B_l[:,k]) * V[t,k], one block per (t-tile, l).
// All 9 k-tiles processed in-block with register accumulation -> direct store.
// Uniform control flow (no divergent barriers); bounds: k0+srow <= 575 < 576,
// h0+scol+8 <= 544. FP delta vs r3 is only the tile-partial summation order.
// ---------------------------------------------------------------------------
__global__ __launch_bounds__(256) void label_mfma(
    const _Float16* __restrict__ Uh, const _Float16* __restrict__ Bh,
    const float* __restrict__ V, float* __restrict__ sel) {
    __shared__ _Float16 Us[64][40];
    __shared__ _Float16 Bs[64][40];
    int l = blockIdx.z;
    int t0 = blockIdx.y * 64;
    int tid = threadIdx.x;
    int w = tid >> 6, lane = tid & 63, m = lane & 15, q = lane >> 4;
    const _Float16* Bl = Bh + (size_t)l * 576 * 544;
    int srow = tid >> 2, scol = (tid & 3) * 8;

    float vt[4] = {0.f, 0.f, 0.f, 0.f};

    for (int k0 = 0; k0 < 576; k0 += 64) {
        f4_t acc[4];
#pragma unroll
        for (int c = 0; c < 4; ++c) acc[c] = 0;

        for (int h0 = 0; h0 < 544; h0 += 32) {
            uint4 ud = *(const uint4*)(Uh + (size_t)(t0 + srow) * 544 + h0 + scol);
            uint4 bd = *(const uint4*)(Bl + (size_t)(k0 + srow) * 544 + h0 + scol);
            __syncthreads();
            *(uint4*)(&Us[srow][scol]) = ud;
            *(uint4*)(&Bs[srow][scol]) = bd;
            __syncthreads();
            h8_t a  = *(const h8_t*)(&Us[w * 16 + m][q * 8]);
            h8_t b0 = *(const h8_t*)(&Bs[ 0 + m][q * 8]);
            h8_t b1 = *(const h8_t*)(&Bs[16 + m][q * 8]);
            h8_t b2 = *(const h8_t*)(&Bs[32 + m][q * 8]);
            h8_t b3 = *(const h8_t*)(&Bs[48 + m][q * 8]);
            acc[0] = __builtin_amdgcn_mfma_f32_16x16x32_f16(a, b0, acc[0], 0, 0, 0);
            acc[1] = __builtin_amdgcn_mfma_f32_16x16x32_f16(a, b1, acc[1], 0, 0, 0);
            acc[2] = __builtin_amdgcn_mfma_f32_16x16x32_f16(a, b2, acc[2], 0, 0, 0);
            acc[3] = __builtin_amdgcn_mfma_f32_16x16x32_f16(a, b3, acc[3], 0, 0, 0);
        }

#pragma unroll
        for (int r = 0; r < 4; ++r) {
            int t = t0 + w * 16 + q * 4 + r;
            float vs = 0.f;
#pragma unroll
            for (int c = 0; c < 4; ++c) {
                int k = k0 + c * 16 + m;
                float vv = (k < 513) ? V[(size_t)t * 516 + k] : 0.f;
                vs += acc[c][r] * vv;
            }
            vt[r] += vs;
        }
    }

    float* selp = sel + (size_t)l * 512;
#pragma unroll
    for (int r = 0; r < 4; ++r) {
        int t = t0 + w * 16 + q * 4 + r;
        float vsum = vt[r];
#pragma unroll
        for (int off = 1; off < 16; off <<= 1)
            vsum += __shfl_xor(vsum, off);
        if (m == 0) selp[t] = vsum;
    }
}

// ---------------------------------------------------------------------------
// Row softmax in place (512x512)
// ---------------------------------------------------------------------------
__global__ __launch_bounds__(256) void softmax_rows(float* __restrict__ Smat) {
    __shared__ float sdata[256];
    int i = blockIdx.x, tid = threadIdx.x;
    float* row = Smat + (size_t)i * 512;
    float m = -1e30f;
    for (int j = tid; j < 512; j += 256) m = fmaxf(m, row[j]);
    sdata[tid] = m; __syncthreads();
    for (int off = 128; off > 0; off >>= 1) {
        if (tid < off) sdata[tid] = fmaxf(sdata[tid], sdata[tid + off]);
        __syncthreads();
    }
    m = sdata[0]; __syncthreads();
    float ssum = 0.f;
    for (int j = tid; j < 512; j += 256) { float e = __expf(row[j] - m); row[j] = e; ssum += e; }
    sdata[tid] = ssum; __syncthreads();
    for (int off = 128; off > 0; off >>= 1) {
        if (tid < off) sdata[tid] += sdata[tid + off];
        __syncthreads();
    }
    float inv = 1.f / sdata[0];
    for (int j = tid; j < 512; j += 256) row[j] *= inv;
}

// ---------------------------------------------------------------------------
// log_softmax over l (50) for each t (512)
// ---------------------------------------------------------------------------
__global__ void lsm_k(const float* __restrict__ sel, float* __restrict__ out1) {
    int t = blockIdx.x * blockDim.x + threadIdx.x;
    if (t >= 512) return;
    float m = -1e30f;
    for (int l = 0; l < 50; ++l) m = fmaxf(m, sel[l * 512 + t]);
    float ssum = 0.f;
    for (int l = 0; l < 50; ++l) ssum += __expf(sel[l * 512 + t] - m);
    float lse = m + __logf(ssum);
    for (int l = 0; l < 50; ++l) out1[l * 512 + t] = sel[l * 512 + t] - lse;
}

// ---------------------------------------------------------------------------
extern "C" void kernel_launch(void* const* d_in, const int* in_sizes, int n_in,
                              void* d_out, int out_size, void* d_ws, size_t ws_size,
                              hipStream_t stream) {
    const int* sentence     = (const int*)d_in[0];
    const int* tags         = (const int*)d_in[1];
    const int* chars        = (const int*)d_in[2];
    const int* char_lengths = (const int*)d_in[3];
    const int* best_arcs    = (const int*)d_in[4];
    const float* word_emb   = (const float*)d_in[5];
    const float* tag_emb    = (const float*)d_in[6];
    const float* char_emb   = (const float*)d_in[7];
    const float* att_W      = (const float*)d_in[8];
    const float* att_b      = (const float*)d_in[9];
    const float* W_ih_f     = (const float*)d_in[10];
    const float* W_hh_f     = (const float*)d_in[11];
    const float* b_f        = (const float*)d_in[12];
    const float* W_ih_b     = (const float*)d_in[13];
    const float* W_hh_b     = (const float*)d_in[14];
    const float* b_b        = (const float*)d_in[15];
    const float* cW_ih      = (const float*)d_in[16];
    const float* cW_hh      = (const float*)d_in[17];
    const float* cb         = (const float*)d_in[18];
    const float* arc_dep_W  = (const float*)d_in[19];
    const float* arc_dep_b  = (const float*)d_in[20];
    const float* arc_head_W = (const float*)d_in[21];
    const float* arc_head_b = (const float*)d_in[22];
    const float* label_dep_W  = (const float*)d_in[23];
    const float* label_dep_b  = (const float*)d_in[24];
    const float* label_head_W = (const float*)d_in[25];
    const float* label_head_b = (const float*)d_in[26];
    const float* biaff_arc_W   = (const float*)d_in[27];
    const float* biaff_label_W = (const float*)d_in[28];

    float* ws = (float*)d_ws;
    float* out = (float*)d_out;

    // workspace layout (float offsets) — round-3 proven layout.
    const size_t o_Wh16   = 0;            // 1048576 (fp16 4x512x1024)
    const size_t o_V      = 204800;       // 264192 (born after heads_mfma)
    const size_t o_Uh     = 468992;       // 139264 (fp16 512x544)
    const size_t o_xf     = 1134592;      // 1048576
    const size_t o_xb     = 2183168;      // 1048576
    const size_t o_lstmh  = 3231744;      // 262144 (fp16 512x1024)
    const size_t o_heads  = 3493888;      // 1048576 region, sub-layout:
    const size_t o_LD     = o_heads + 0;       // fp32 512x512   (262144)
    const size_t o_AD16   = o_heads + 262144;  // fp16 512x512   (131072)
    const size_t o_AH16   = o_heads + 393216;  // fp16 512x544   (139264)
    const size_t o_LH16   = o_heads + 532480;  // fp16 512x544   (139264)
    const size_t o_P16    = o_heads + 671744;  // fp16 512x512   (131072)
    const size_t o_Warc16 = o_heads + 802816;  // fp16 512x544   (139264) -> ends 942080
    const size_t o_sel    = 4542464;      // 25600
    const size_t o_hG     = 4568064;      // 2048 (1024 qwords)
    const size_t o_Bh     = 4570112;      // 7833600 (fp16 50x576x544) -> ends 12403712

    hipMemsetAsync(ws + o_hG, 0, 8192, stream);
    hipMemsetAsync(ws + o_sel, 0, 25600 * sizeof(float), stream);

    // input projections (with fused embedding gather) — the LSTM's only prereq
    xproj_k<<<512, 256, 0, stream>>>(sentence, tags, word_emb, tag_emb,
                                     W_ih_f, b_f, ws + o_xf,
                                     W_ih_b, b_b, ws + o_xb);

    // biLSTM (proven agent-scope exchange) + all lstm-independent prep fused
    fused_k<<<6130, 256, 0, stream>>>(
        W_hh_f, W_hh_b, ws + o_xf, ws + o_xb,
        (_Float16*)(ws + o_lstmh), (unsigned long long*)(ws + o_hG),
        biaff_label_W, (_Float16*)(ws + o_Bh),
        chars, char_lengths, char_emb, att_W, att_b, cW_ih, cW_hh, cb,
        out + 287744,
        biaff_arc_W, (_Float16*)(ws + o_Warc16),
        arc_dep_W, arc_head_W, label_dep_W, label_head_W,
        (_Float16*)(ws + o_Wh16));

    heads_mfma<<<dim3(8, 8, 4), 256, 0, stream>>>(
        (const _Float16*)(ws + o_lstmh), (const _Float16*)(ws + o_Wh16),
        arc_dep_b, arc_head_b, label_dep_b, label_head_b,
        (_Float16*)(ws + o_AD16), (_Float16*)(ws + o_AH16),
        ws + o_LD, (_Float16*)(ws + o_LH16));

    uv2_k<<<512, 128, 0, stream>>>(best_arcs, (const _Float16*)(ws + o_LH16),
                                   ws + o_LD, (_Float16*)(ws + o_Uh), ws + o_V);

    // arc path: P16 = AH16 @ W16arc^T (K=544), S = P16 @ AD16^T (K=512) -> out
    gemm16_mfma<<<dim3(8, 8), 256, 0, stream>>>(
        (const _Float16*)(ws + o_AH16), 544, (const _Float16*)(ws + o_Warc16), 544, 544,
        (_Float16*)(ws + o_P16), nullptr);
    gemm16_mfma<<<dim3(8, 8), 256, 0, stream>>>(
        (const _Float16*)(ws + o_P16), 512, (const _Float16*)(ws + o_AD16), 512, 512,
        nullptr, out);
    softmax_rows<<<512, 256, 0, stream>>>(out);

    label_mfma<<<dim3(1, 8, 50), 256, 0, stream>>>(
        (const _Float16*)(ws + o_Uh), (const _Float16*)(ws + o_Bh),
        ws + o_V, ws + o_sel);
    lsm_k<<<2, 256, 0, stream>>>(ws + o_sel, out + 262144);
}

// Round 7
// 1303.359 us; speedup vs baseline: 1.0859x; 1.0859x over previous
//
#include <hip/hip_runtime.h>
#include <hip/hip_fp16.h>

// ---------------------------------------------------------------------------
// Problem constants
//   S=512 tokens, WD=300, TD=100, CE=20, CH=20, H=512, LAB=50, MAXW=16
// Outputs: arc_scores (512x512) | label_scores (50x512) | char_embeds (20x512)
//
// Round-7 structure:
//   - LSTM core + fused_k: BYTE-IDENTICAL to r3/r6 (twice-proven, 950us).
//   - label_mfma: r3 atomic 3600-block form (r6 proved K-merge = -120us:
//     400 blocks can't hide staging latency; 3600 blocks pipeline each other).
//   - Tail launch-merge: {gemm1 || label} -> tail1, {gemm2 || lsm} -> tail2,
//     softmax last. 9 dispatches -> 6; independent deps verified.
// ---------------------------------------------------------------------------

static __device__ __forceinline__ float sigm(float x) { return 1.f / (1.f + __expf(-x)); }
static __device__ __forceinline__ float ftanh(float x) {
    x = fminf(15.f, fmaxf(-15.f, x));
    float e = __expf(2.f * x);
    return (e - 1.f) / (e + 1.f);
}

typedef _Float16 h2_t __attribute__((ext_vector_type(2)));
typedef _Float16 h8_t __attribute__((ext_vector_type(8)));
typedef float f4_t __attribute__((ext_vector_type(4)));
union U32H2 { unsigned u; h2_t h; unsigned short s[2]; };

static __device__ __forceinline__ float dot2f(unsigned wa, unsigned hb, float c) {
#if __has_builtin(__builtin_amdgcn_fdot2)
    U32H2 a, b; a.u = wa; b.u = hb;
    return __builtin_amdgcn_fdot2(a.h, b.h, c, false);
#else
    U32H2 a, b; a.u = wa; b.u = hb;
    return c + (float)a.h[0] * (float)b.h[0] + (float)a.h[1] * (float)b.h[1];
#endif
}
static __device__ __forceinline__ unsigned short f2h16(float x) {
    return __half_as_ushort(__float2half(x));
}

// ---------------------------------------------------------------------------
// h-queue primitives: agent-scope relaxed atomics. PROVEN (r0/r3/r6). The sc0
// fast path stays shelved (r1/r2/r4 hang family); r5's LSTM micro-opt bundle
// also hung opaquely and is withheld from this round.
// ---------------------------------------------------------------------------
static __device__ __forceinline__ unsigned long long hq_ld(const unsigned long long* p) {
    return __hip_atomic_load(p, __ATOMIC_RELAXED, __HIP_MEMORY_SCOPE_AGENT);
}
static __device__ __forceinline__ void hq_st(unsigned long long* p, unsigned long long v) {
    __hip_atomic_store(p, v, __ATOMIC_RELAXED, __HIP_MEMORY_SCOPE_AGENT);
}

// ---------------------------------------------------------------------------
// Recurrent biLSTM core — r3/r6 body VERBATIM (measured 950us twice).
// ---------------------------------------------------------------------------
static __device__ void lstm_core(int dir, int s, int tid,
                                 const float* __restrict__ Whh,
                                 const float* __restrict__ xp,
                                 _Float16* __restrict__ lstmh,
                                 unsigned long long* __restrict__ hq,
                                 float* __restrict__ red /* 2*1024 floats LDS */) {
    int lane = tid & 63;
    int g = tid & 31, p = tid >> 5;

    unsigned Wreg[4][32];
#pragma unroll
    for (int q = 0; q < 4; ++q) {
        int gr = q * 512 + s * 32 + g;
        const float* wrow = Whh + (size_t)gr * 512 + p * 64;
#pragma unroll
        for (int u = 0; u < 32; ++u) {
            unsigned lo = f2h16(wrow[2 * u]);
            unsigned hi = f2h16(wrow[2 * u + 1]);
            Wreg[q][u] = lo | (hi << 16);
        }
    }

    float c = 0.f;
    unsigned long long* hbase = hq + dir * 512;
    int qidx = tid;

    for (int t = 0; t < 512; ++t) {
        float x0 = 0.f, x1 = 0.f, x2 = 0.f, x3 = 0.f;
        if (tid < 32) {
            const float* x = xp + (size_t)t * 2048;
            int col = s * 32 + tid;
            x0 = x[col]; x1 = x[512 + col]; x2 = x[1024 + col]; x3 = x[1536 + col];
        }

        unsigned long long* hin = hbase + (t & 1) * 256;
        unsigned tag = (unsigned)t & 0xffffu;
        unsigned long long v = hq_ld(hin + qidx);
        while ((((unsigned)(v >> 16)) & 0xffffu) != tag || ((unsigned)(v >> 48)) != tag)
            v = hq_ld(hin + qidx);
        unsigned hw = (unsigned)(v & 0xffffu) | (((unsigned)((v >> 32) & 0xffffu)) << 16);

        float a0 = 0.f, a1 = 0.f, a2 = 0.f, a3 = 0.f;
        int half_base = lane & 32;
#pragma unroll
        for (int u = 0; u < 32; ++u) {
            unsigned hwu = (unsigned)__shfl((int)hw, half_base + u);
            a0 = dot2f(Wreg[0][u], hwu, a0);
            a1 = dot2f(Wreg[1][u], hwu, a1);
            a2 = dot2f(Wreg[2][u], hwu, a2);
            a3 = dot2f(Wreg[3][u], hwu, a3);
        }
        float* r = red + (t & 1) * 1024 + p * 128 + g * 4;
        r[0] = a0; r[1] = a1; r[2] = a2; r[3] = a3;
        __syncthreads();

        if (tid < 32) {
            float z0 = 0.f, z1 = 0.f, z2 = 0.f, z3 = 0.f;
            const float* rb = red + (t & 1) * 1024;
#pragma unroll
            for (int pp = 0; pp < 8; ++pp) {
                const float* rr = rb + pp * 128 + tid * 4;
                z0 += rr[0]; z1 += rr[1]; z2 += rr[2]; z3 += rr[3];
            }
            z0 += x0; z1 += x1; z2 += x2; z3 += x3;
            c = sigm(z1) * c + sigm(z0) * ftanh(z2);
            float hn = sigm(z3) * ftanh(c);
            int col = s * 32 + tid;
            int row = dir ? (511 - t) : t;
            lstmh[(size_t)row * 1024 + dir * 512 + col] = (_Float16)hn;

            unsigned tw = (unsigned)f2h16(hn) | (((unsigned)(t + 1) & 0xffffu) << 16);
            unsigned other = (unsigned)__shfl_down((int)tw, 1);
            if ((tid & 1) == 0) {
                unsigned long long qv = (unsigned long long)tw |
                                        ((unsigned long long)other << 32);
                hq_st(hbase + ((t + 1) & 1) * 256 + (col >> 1), qv);
            }
        }
    }
}

// ---------------------------------------------------------------------------
// Shared 64x64 fp16 MFMA GEMM tile body (A[M,K]@B[N,K]^T), used by tail1/tail2.
// Identical math/LDS structure to the proven gemm16_mfma kernel.
// ---------------------------------------------------------------------------
typedef _Float16 SRow40[40];
static __device__ void gemm_tile64(const _Float16* __restrict__ A, int lda,
                                   const _Float16* __restrict__ B, int ldb, int K,
                                   _Float16* __restrict__ C16, float* __restrict__ C32,
                                   int m0, int n0, int tid,
                                   SRow40* As, SRow40* Bs) {
    int w = tid >> 6, lane = tid & 63, m = lane & 15, q = lane >> 4;
    int srow = tid >> 2, scol = (tid & 3) * 8;

    f4_t acc[4];
#pragma unroll
    for (int cc = 0; cc < 4; ++cc) acc[cc] = 0;

    for (int k0 = 0; k0 < K; k0 += 32) {
        uint4 ad = *(const uint4*)(A + (size_t)(m0 + srow) * lda + k0 + scol);
        uint4 bd = *(const uint4*)(B + (size_t)(n0 + srow) * ldb + k0 + scol);
        __syncthreads();
        *(uint4*)(&As[srow][scol]) = ad;
        *(uint4*)(&Bs[srow][scol]) = bd;
        __syncthreads();
        h8_t a  = *(const h8_t*)(&As[w * 16 + m][q * 8]);
        h8_t b0 = *(const h8_t*)(&Bs[ 0 + m][q * 8]);
        h8_t b1 = *(const h8_t*)(&Bs[16 + m][q * 8]);
        h8_t b2 = *(const h8_t*)(&Bs[32 + m][q * 8]);
        h8_t b3 = *(const h8_t*)(&Bs[48 + m][q * 8]);
        acc[0] = __builtin_amdgcn_mfma_f32_16x16x32_f16(a, b0, acc[0], 0, 0, 0);
        acc[1] = __builtin_amdgcn_mfma_f32_16x16x32_f16(a, b1, acc[1], 0, 0, 0);
        acc[2] = __builtin_amdgcn_mfma_f32_16x16x32_f16(a, b2, acc[2], 0, 0, 0);
        acc[3] = __builtin_amdgcn_mfma_f32_16x16x32_f16(a, b3, acc[3], 0, 0, 0);
    }
#pragma unroll
    for (int r = 0; r < 4; ++r) {
        int row = m0 + w * 16 + q * 4 + r;
#pragma unroll
        for (int cc = 0; cc < 4; ++cc) {
            int ncol = n0 + cc * 16 + m;
            if (C16) C16[(size_t)row * 512 + ncol] = (_Float16)acc[cc][r];
            else     C32[(size_t)row * 512 + ncol] = acc[cc][r];
        }
    }
}

// ---------------------------------------------------------------------------
// xproj (fp32 tile GEMM) with FUSED embedding gather — r3 verbatim.
// ---------------------------------------------------------------------------
__global__ __launch_bounds__(256) void xproj_k(
    const int* __restrict__ sentence, const int* __restrict__ tags,
    const float* __restrict__ word_emb, const float* __restrict__ tag_emb,
    const float* __restrict__ Wf, const float* __restrict__ bf, float* __restrict__ Cf,
    const float* __restrict__ Wb, const float* __restrict__ bb, float* __restrict__ Cb) {
    __shared__ float smemf[2 * 16 * 65];
    typedef float Row65[65];
    Row65* As = (Row65*)smemf;
    Row65* Bs = (Row65*)(smemf + 16 * 65);
    int idx = blockIdx.x;
    int z = idx >> 8, rem = idx & 255;
    int bn = (rem & 31) * 64, bm = (rem >> 5) * 64;
    const float* W = z ? Wb : Wf;
    const float* bias = z ? bb : bf;
    float* C = z ? Cb : Cf;
    int tx = threadIdx.x & 15, ty = threadIdx.x >> 4;
    float acc[4][4] = {};
    for (int k0 = 0; k0 < 400; k0 += 16) {
#pragma unroll
        for (int i = 0; i < 4; ++i) {
            int e = threadIdx.x + i * 256;
            int m = e >> 4, kk = e & 15;
            int row = bm + m; if (z) row = 511 - row;
            int k = k0 + kk;
            float av = (k < 300) ? word_emb[(size_t)sentence[row] * 300 + k]
                                 : tag_emb[(size_t)tags[row] * 100 + (k - 300)];
            As[kk][m] = av;
            Bs[kk][m] = W[(size_t)(bn + m) * 400 + k];
        }
        __syncthreads();
#pragma unroll
        for (int kk = 0; kk < 16; ++kk) {
            float a0 = As[kk][ty * 4 + 0], a1 = As[kk][ty * 4 + 1];
            float a2 = As[kk][ty * 4 + 2], a3 = As[kk][ty * 4 + 3];
            float b0 = Bs[kk][tx * 4 + 0], b1 = Bs[kk][tx * 4 + 1];
            float b2 = Bs[kk][tx * 4 + 2], b3 = Bs[kk][tx * 4 + 3];
            acc[0][0] += a0 * b0; acc[0][1] += a0 * b1; acc[0][2] += a0 * b2; acc[0][3] += a0 * b3;
            acc[1][0] += a1 * b0; acc[1][1] += a1 * b1; acc[1][2] += a1 * b2; acc[1][3] += a1 * b3;
            acc[2][0] += a2 * b0; acc[2][1] += a2 * b1; acc[2][2] += a2 * b2; acc[2][3] += a2 * b3;
            acc[3][0] += a3 * b0; acc[3][1] += a3 * b1; acc[3][2] += a3 * b2; acc[3][3] += a3 * b3;
        }
        __syncthreads();
    }
#pragma unroll
    for (int i = 0; i < 4; ++i) {
#pragma unroll
        for (int j = 0; j < 4; ++j) {
            int n = bn + tx * 4 + j;
            C[(size_t)(bm + ty * 4 + i) * 2048 + n] = acc[i][j] + bias[n];
        }
    }
}

// ---------------------------------------------------------------------------
// FUSED kernel — r3/r6 VERBATIM (twice-proven):
//   [   0,  32) biLSTM (dir = bid>>4, s = bid&15)
//   [  32, 544) char LSTM + gram attention (512)
//   [ 544,1568) hconv: 4 head weight mats fp32->fp16 (1024)
//   [1568,2080) warc conv fp32[512][513] -> fp16[512][544] (512)
//   [2080,6130) bconv: biaff_label_W -> fp16 [l][k][h] (4050)
// ---------------------------------------------------------------------------
__global__ __launch_bounds__(256) void fused_k(
    const float* __restrict__ W_hh_f, const float* __restrict__ W_hh_b,
    const float* __restrict__ xpf, const float* __restrict__ xpb,
    _Float16* __restrict__ lstmh, unsigned long long* __restrict__ hq,
    const float* __restrict__ BW, _Float16* __restrict__ Bh,
    const int* __restrict__ chars, const int* __restrict__ char_lengths,
    const float* __restrict__ char_emb, const float* __restrict__ att_W,
    const float* __restrict__ att_b, const float* __restrict__ cW_ih,
    const float* __restrict__ cW_hh, const float* __restrict__ cb,
    float* __restrict__ out2,
    const float* __restrict__ Warc, _Float16* __restrict__ W16arc,
    const float* __restrict__ hw0, const float* __restrict__ hw1,
    const float* __restrict__ hw2, const float* __restrict__ hw3,
    _Float16* __restrict__ Wh16) {
    __shared__ __align__(16) unsigned char smem[16384];
    int bid = blockIdx.x;
    int tid = threadIdx.x;

    if (bid < 32) {
        // ---------------- biLSTM ----------------
        int dir = bid >> 4, s = bid & 15;
        const float* Whh = dir ? W_hh_b : W_hh_f;
        const float* xp = dir ? xpb : xpf;
        lstm_core(dir, s, tid, Whh, xp, lstmh, hq, (float*)smem);
    } else if (bid < 544) {
        // ---------------- char LSTM + gram attention ----------------
        float* Wih = (float*)smem;
        float* Whh2 = Wih + 1600;
        float* cbs = Whh2 + 1600;
        float* attsh = cbs + 80;
        float* xsh = attsh + 20;
        float* hsh = xsh + 20;
        float* prodsh = hsh + 20;
        int wd = bid - 32;
        for (int i = tid; i < 1600; i += 256) { Wih[i] = cW_ih[i]; Whh2[i] = cW_hh[i]; }
        for (int i = tid; i < 80; i += 256) cbs[i] = cb[i];
        if (tid < 20) { attsh[tid] = att_W[tid]; hsh[tid] = 0.f; }
        __syncthreads();

        int L = char_lengths[wd];
        float c = 0.f, accj = 0.f;
        for (int t = 0; t < 16; ++t) {
            if (tid < 20) xsh[tid] = char_emb[(size_t)chars[wd * 16 + t] * 20 + tid];
            __syncthreads();
            float hn = 0.f;
            if (tid < 20) {
                float z[4];
#pragma unroll
                for (int q = 0; q < 4; ++q) {
                    int rr = q * 20 + tid;
                    float sacc = cbs[rr];
                    for (int d = 0; d < 20; ++d)
                        sacc += Wih[rr * 20 + d] * xsh[d] + Whh2[rr * 20 + d] * hsh[d];
                    z[q] = sacc;
                }
                c = sigm(z[1]) * c + sigm(z[0]) * ftanh(z[2]);
                hn = sigm(z[3]) * ftanh(c);
            }
            __syncthreads();
            if (tid < 20) { hsh[tid] = hn; prodsh[tid] = hn * attsh[tid]; }
            __syncthreads();
            if (tid < 20 && t < L) {
                float st = 0.f;
                for (int k = 0; k < 20; ++k) st += prodsh[k];
                accj += hn * st;
            }
            __syncthreads();
        }
        if (tid < 20) out2[tid * 512 + wd] = accj + att_b[0];
    } else if (bid < 1568) {
        // ---------------- hconv: 4 head weight matrices fp32 -> fp16 --------
        size_t e0 = ((size_t)(bid - 544) * 256 + tid) * 8;
        int mat = (int)(e0 >> 19);
        size_t off = e0 & 524287;
        const float* src = (mat == 0 ? hw0 : mat == 1 ? hw1 : mat == 2 ? hw2 : hw3) + off;
        float4 f0 = ((const float4*)src)[0];
        float4 f1 = ((const float4*)src)[1];
        __align__(16) _Float16 hv[8];
        hv[0] = (_Float16)f0.x; hv[1] = (_Float16)f0.y;
        hv[2] = (_Float16)f0.z; hv[3] = (_Float16)f0.w;
        hv[4] = (_Float16)f1.x; hv[5] = (_Float16)f1.y;
        hv[6] = (_Float16)f1.z; hv[7] = (_Float16)f1.w;
        *(uint4*)(Wh16 + e0) = *(const uint4*)hv;
    } else if (bid < 2080) {
        // ---------------- warc conv: [512][513] fp32 -> [512][544] fp16 -----
        int t = bid - 1568;
        for (int j = tid; j < 544; j += 256)
            W16arc[(size_t)t * 544 + j] = (_Float16)((j < 513) ? Warc[(size_t)t * 513 + j] : 0.f);
    } else {
        // ---------------- bconv ----------------
        typedef _Float16 TsRow[68];
        TsRow* Ts = (TsRow*)smem;
        int b2 = bid - 2080;
        int lb = b2 / 81, rem = b2 % 81;
        int h0 = (rem % 9) * 64, k0 = (rem / 9) * 64;
        const float* Bl = BW + (size_t)lb * 513 * 513;
        _Float16* BhL = Bh + (size_t)lb * 576 * 544;
        int tr = tid >> 4, tc = tid & 15;
#pragma unroll
        for (int i = 0; i < 4; ++i) {
            int hl = tr + i * 16;
            int h = h0 + hl;
#pragma unroll
            for (int j = 0; j < 4; ++j) {
                int k = k0 + tc * 4 + j;
                float v = (h < 513 && k < 513) ? Bl[(size_t)h * 513 + k] : 0.f;
                Ts[hl][tc * 4 + j] = (_Float16)v;
            }
        }
        __syncthreads();
        int cr = tid >> 2, hb = (tid & 3) * 16;
        int hg = h0 + hb;
        if (hg < 544) {
            __align__(16) _Float16 tmp[16];
#pragma unroll
            for (int j = 0; j < 16; ++j) tmp[j] = Ts[hb + j][cr];
            uint4* dst = (uint4*)(BhL + (size_t)(k0 + cr) * 544 + hg);
            dst[0] = ((const uint4*)tmp)[0];
            dst[1] = ((const uint4*)tmp)[1];
        }
    }
}

// ---------------------------------------------------------------------------
// Heads MFMA — r3 verbatim.
// ---------------------------------------------------------------------------
__global__ __launch_bounds__(256) void heads_mfma(
    const _Float16* __restrict__ A, const _Float16* __restrict__ Wh,
    const float* __restrict__ b0, const float* __restrict__ b1,
    const float* __restrict__ b2, const float* __restrict__ b3,
    _Float16* __restrict__ AD16, _Float16* __restrict__ AH16,
    float* __restrict__ LD, _Float16* __restrict__ LH16) {
    __shared__ _Float16 As[64][40];
    __shared__ _Float16 Bs[64][40];
    int hd = blockIdx.z;
    int m0 = blockIdx.y * 64, n0 = blockIdx.x * 64;
    const _Float16* Bp = Wh + (size_t)hd * 512 * 1024;
    const float* bias = (hd == 0) ? b0 : (hd == 1) ? b1 : (hd == 2) ? b2 : b3;
    int tid = threadIdx.x;
    int w = tid >> 6, lane = tid & 63, m = lane & 15, q = lane >> 4;
    int srow = tid >> 2, scol = (tid & 3) * 8;

    f4_t acc[4];
#pragma unroll
    for (int cc = 0; cc < 4; ++cc) acc[cc] = 0;

    for (int k0 = 0; k0 < 1024; k0 += 32) {
        uint4 ad = *(const uint4*)(A + (size_t)(m0 + srow) * 1024 + k0 + scol);
        uint4 bd = *(const uint4*)(Bp + (size_t)(n0 + srow) * 1024 + k0 + scol);
        __syncthreads();
        *(uint4*)(&As[srow][scol]) = ad;
        *(uint4*)(&Bs[srow][scol]) = bd;
        __syncthreads();
        h8_t a  = *(const h8_t*)(&As[w * 16 + m][q * 8]);
        h8_t bb0 = *(const h8_t*)(&Bs[ 0 + m][q * 8]);
        h8_t bb1 = *(const h8_t*)(&Bs[16 + m][q * 8]);
        h8_t bb2 = *(const h8_t*)(&Bs[32 + m][q * 8]);
        h8_t bb3 = *(const h8_t*)(&Bs[48 + m][q * 8]);
        acc[0] = __builtin_amdgcn_mfma_f32_16x16x32_f16(a, bb0, acc[0], 0, 0, 0);
        acc[1] = __builtin_amdgcn_mfma_f32_16x16x32_f16(a, bb1, acc[1], 0, 0, 0);
        acc[2] = __builtin_amdgcn_mfma_f32_16x16x32_f16(a, bb2, acc[2], 0, 0, 0);
        acc[3] = __builtin_amdgcn_mfma_f32_16x16x32_f16(a, bb3, acc[3], 0, 0, 0);
    }
#pragma unroll
    for (int r = 0; r < 4; ++r) {
        int row = m0 + w * 16 + q * 4 + r;
#pragma unroll
        for (int cc = 0; cc < 4; ++cc) {
            int ncol = n0 + cc * 16 + m;
            float v = fmaxf(acc[cc][r] + bias[ncol], 0.f);
            if (hd == 2)      LD[(size_t)row * 512 + ncol] = v;
            else if (hd == 0) AD16[(size_t)row * 512 + ncol] = (_Float16)v;
            else {
                _Float16* dst = (hd == 1) ? AH16 : LH16;
                dst[(size_t)row * 544 + ncol] = (_Float16)v;
            }
        }
    }
    // ones + zero-pad columns (512..543) for the 544-stride fp16 heads
    if ((hd == 1 || hd == 3) && blockIdx.x == 7 && tid < 64) {
        _Float16* dst = (hd == 1) ? AH16 : LH16;
        int row = m0 + tid;
        dst[(size_t)row * 544 + 512] = (_Float16)1.f;
        for (int j = 513; j < 544; ++j) dst[(size_t)row * 544 + j] = (_Float16)0.f;
    }
}

// ---------------------------------------------------------------------------
// uv2: Uh[t] = LH16[best_arcs[t]] (fp16 row copy, 544), V[t] = [LD[t],1,pad0]
// ---------------------------------------------------------------------------
__global__ void uv2_k(const int* __restrict__ best_arcs,
                      const _Float16* __restrict__ LH16, const float* __restrict__ LD,
                      _Float16* __restrict__ Uh, float* __restrict__ V) {
    int t = blockIdx.x;
    int ba = best_arcs[t];
    const unsigned* src = (const unsigned*)(LH16 + (size_t)ba * 544);
    unsigned* dst = (unsigned*)(Uh + (size_t)t * 544);
    for (int j = threadIdx.x; j < 272; j += blockDim.x) dst[j] = src[j];
    for (int j = threadIdx.x; j < 516; j += blockDim.x)
        V[t * 516 + j] = (j < 512) ? LD[(size_t)t * 512 + j] : (j == 512 ? 1.f : 0.f);
}

// ---------------------------------------------------------------------------
// tail1: blocks [0,64) = gemm1 (P16 = AH16 @ Warc16^T, K=544, fp16 out);
//        blocks [64,3664) = label biaffine, r3 ATOMIC 3600-block form
//        (r6 proved the 400-block K-merge costs ~120us — parallelism matters).
// Dependencies: gemm1 needs AH16/Warc16 (heads_mfma/fused_k done);
//               label needs Uh/V (uv2 done) + Bh (fused_k done). Independent.
// ---------------------------------------------------------------------------
__global__ __launch_bounds__(256) void tail1_k(
    const _Float16* __restrict__ AH16, const _Float16* __restrict__ Warc16,
    _Float16* __restrict__ P16,
    const _Float16* __restrict__ Uh, const _Float16* __restrict__ Bh,
    const float* __restrict__ V, float* __restrict__ sel) {
    __shared__ _Float16 As[64][40];
    __shared__ _Float16 Bs[64][40];
    int bid = blockIdx.x;
    int tid = threadIdx.x;

    if (bid < 64) {
        gemm_tile64(AH16, 544, Warc16, 544, 544, P16, nullptr,
                    (bid >> 3) * 64, (bid & 7) * 64, tid, (SRow40*)As, (SRow40*)Bs);
        return;
    }

    // ---------------- label biaffine (r3 atomic body) ----------------
    int b2 = bid - 64;
    int kx = b2 % 9, ty2 = (b2 / 9) % 8, l = b2 / 72;
    int t0 = ty2 * 64, k0 = kx * 64;
    int w = tid >> 6, lane = tid & 63, m = lane & 15, q = lane >> 4;
    const _Float16* Bl = Bh + (size_t)l * 576 * 544;
    int srow = tid >> 2, scol = (tid & 3) * 8;

    f4_t acc[4];
#pragma unroll
    for (int c = 0; c < 4; ++c) acc[c] = 0;

    for (int h0 = 0; h0 < 544; h0 += 32) {
        uint4 ud = *(const uint4*)(Uh + (size_t)(t0 + srow) * 544 + h0 + scol);
        uint4 bd = *(const uint4*)(Bl + (size_t)(k0 + srow) * 544 + h0 + scol);
        __syncthreads();
        *(uint4*)(&As[srow][scol]) = ud;
        *(uint4*)(&Bs[srow][scol]) = bd;
        __syncthreads();
        h8_t a  = *(const h8_t*)(&As[w * 16 + m][q * 8]);
        h8_t b0 = *(const h8_t*)(&Bs[ 0 + m][q * 8]);
        h8_t b1 = *(const h8_t*)(&Bs[16 + m][q * 8]);
        h8_t b2v = *(const h8_t*)(&Bs[32 + m][q * 8]);
        h8_t b3 = *(const h8_t*)(&Bs[48 + m][q * 8]);
        acc[0] = __builtin_amdgcn_mfma_f32_16x16x32_f16(a, b0, acc[0], 0, 0, 0);
        acc[1] = __builtin_amdgcn_mfma_f32_16x16x32_f16(a, b1, acc[1], 0, 0, 0);
        acc[2] = __builtin_amdgcn_mfma_f32_16x16x32_f16(a, b2v, acc[2], 0, 0, 0);
        acc[3] = __builtin_amdgcn_mfma_f32_16x16x32_f16(a, b3, acc[3], 0, 0, 0);
    }

    float* selp = sel + (size_t)l * 512;
#pragma unroll
    for (int r = 0; r < 4; ++r) {
        int t = t0 + w * 16 + q * 4 + r;
        float vsum = 0.f;
#pragma unroll
        for (int c = 0; c < 4; ++c) {
            int k = k0 + c * 16 + m;
            float vv = (k < 513) ? V[(size_t)t * 516 + k] : 0.f;
            vsum += acc[c][r] * vv;
        }
#pragma unroll
        for (int off = 1; off < 16; off <<= 1)
            vsum += __shfl_xor(vsum, off);
        if (m == 0) atomicAdd(selp + t, vsum);
    }
}

// ---------------------------------------------------------------------------
// tail2: blocks [0,64) = gemm2 (S = P16 @ AD16^T, K=512, fp32 out -> out);
//        blocks [64,66) = lsm (log_softmax over l for each t).
// Dependencies: gemm2 needs P16 (tail1 gemm part); lsm needs sel (tail1 label
// part). Both satisfied after tail1; the two roles touch disjoint memory.
// ---------------------------------------------------------------------------
__global__ __launch_bounds__(256) void tail2_k(
    const _Float16* __restrict__ P16, const _Float16* __restrict__ AD16,
    float* __restrict__ Smat,
    const float* __restrict__ sel, float* __restrict__ out1) {
    __shared__ _Float16 As[64][40];
    __shared__ _Float16 Bs[64][40];
    int bid = blockIdx.x;
    int tid = threadIdx.x;

    if (bid < 64) {
        gemm_tile64(P16, 512, AD16, 512, 512, nullptr, Smat,
                    (bid >> 3) * 64, (bid & 7) * 64, tid, (SRow40*)As, (SRow40*)Bs);
        return;
    }
    int t = (bid - 64) * 256 + tid;
    if (t >= 512) return;
    float m = -1e30f;
    for (int l = 0; l < 50; ++l) m = fmaxf(m, sel[l * 512 + t]);
    float ssum = 0.f;
    for (int l = 0; l < 50; ++l) ssum += __expf(sel[l * 512 + t] - m);
    float lse = m + __logf(ssum);
    for (int l = 0; l < 50; ++l) out1[l * 512 + t] = sel[l * 512 + t] - lse;
}

// ---------------------------------------------------------------------------
// Row softmax in place (512x512) — runs last (arc region only).
// ---------------------------------------------------------------------------
__global__ __launch_bounds__(256) void softmax_rows(float* __restrict__ Smat) {
    __shared__ float sdata[256];
    int i = blockIdx.x, tid = threadIdx.x;
    float* row = Smat + (size_t)i * 512;
    float m = -1e30f;
    for (int j = tid; j < 512; j += 256) m = fmaxf(m, row[j]);
    sdata[tid] = m; __syncthreads();
    for (int off = 128; off > 0; off >>= 1) {
        if (tid < off) sdata[tid] = fmaxf(sdata[tid], sdata[tid + off]);
        __syncthreads();
    }
    m = sdata[0]; __syncthreads();
    float ssum = 0.f;
    for (int j = tid; j < 512; j += 256) { float e = __expf(row[j] - m); row[j] = e; ssum += e; }
    sdata[tid] = ssum; __syncthreads();
    for (int off = 128; off > 0; off >>= 1) {
        if (tid < off) sdata[tid] += sdata[tid + off];
        __syncthreads();
    }
    float inv = 1.f / sdata[0];
    for (int j = tid; j < 512; j += 256) row[j] *= inv;
}

// ---------------------------------------------------------------------------
extern "C" void kernel_launch(void* const* d_in, const int* in_sizes, int n_in,
                              void* d_out, int out_size, void* d_ws, size_t ws_size,
                              hipStream_t stream) {
    const int* sentence     = (const int*)d_in[0];
    const int* tags         = (const int*)d_in[1];
    const int* chars        = (const int*)d_in[2];
    const int* char_lengths = (const int*)d_in[3];
    const int* best_arcs    = (const int*)d_in[4];
    const float* word_emb   = (const float*)d_in[5];
    const float* tag_emb    = (const float*)d_in[6];
    const float* char_emb   = (const float*)d_in[7];
    const float* att_W      = (const float*)d_in[8];
    const float* att_b      = (const float*)d_in[9];
    const float* W_ih_f     = (const float*)d_in[10];
    const float* W_hh_f     = (const float*)d_in[11];
    const float* b_f        = (const float*)d_in[12];
    const float* W_ih_b     = (const float*)d_in[13];
    const float* W_hh_b     = (const float*)d_in[14];
    const float* b_b        = (const float*)d_in[15];
    const float* cW_ih      = (const float*)d_in[16];
    const float* cW_hh      = (const float*)d_in[17];
    const float* cb         = (const float*)d_in[18];
    const float* arc_dep_W  = (const float*)d_in[19];
    const float* arc_dep_b  = (const float*)d_in[20];
    const float* arc_head_W = (const float*)d_in[21];
    const float* arc_head_b = (const float*)d_in[22];
    const float* label_dep_W  = (const float*)d_in[23];
    const float* label_dep_b  = (const float*)d_in[24];
    const float* label_head_W = (const float*)d_in[25];
    const float* label_head_b = (const float*)d_in[26];
    const float* biaff_arc_W   = (const float*)d_in[27];
    const float* biaff_label_W = (const float*)d_in[28];

    float* ws = (float*)d_ws;
    float* out = (float*)d_out;

    // workspace layout (float offsets) — round-3 proven layout.
    const size_t o_Wh16   = 0;            // 1048576 (fp16 4x512x1024)
    const size_t o_V      = 204800;       // 264192 (born after heads_mfma)
    const size_t o_Uh     = 468992;       // 139264 (fp16 512x544)
    const size_t o_xf     = 1134592;      // 1048576
    const size_t o_xb     = 2183168;      // 1048576
    const size_t o_lstmh  = 3231744;      // 262144 (fp16 512x1024)
    const size_t o_heads  = 3493888;      // 1048576 region, sub-layout:
    const size_t o_LD     = o_heads + 0;       // fp32 512x512   (262144)
    const size_t o_AD16   = o_heads + 262144;  // fp16 512x512   (131072)
    const size_t o_AH16   = o_heads + 393216;  // fp16 512x544   (139264)
    const size_t o_LH16   = o_heads + 532480;  // fp16 512x544   (139264)
    const size_t o_P16    = o_heads + 671744;  // fp16 512x512   (131072)
    const size_t o_Warc16 = o_heads + 802816;  // fp16 512x544   (139264) -> ends 942080
    const size_t o_sel    = 4542464;      // 25600
    const size_t o_hG     = 4568064;      // 2048 (1024 qwords)
    const size_t o_Bh     = 4570112;      // 7833600 (fp16 50x576x544) -> ends 12403712

    hipMemsetAsync(ws + o_hG, 0, 8192, stream);
    hipMemsetAsync(ws + o_sel, 0, 25600 * sizeof(float), stream);

    // input projections (with fused embedding gather) — the LSTM's only prereq
    xproj_k<<<512, 256, 0, stream>>>(sentence, tags, word_emb, tag_emb,
                                     W_ih_f, b_f, ws + o_xf,
                                     W_ih_b, b_b, ws + o_xb);

    // biLSTM (proven agent-scope exchange) + all lstm-independent prep fused
    fused_k<<<6130, 256, 0, stream>>>(
        W_hh_f, W_hh_b, ws + o_xf, ws + o_xb,
        (_Float16*)(ws + o_lstmh), (unsigned long long*)(ws + o_hG),
        biaff_label_W, (_Float16*)(ws + o_Bh),
        chars, char_lengths, char_emb, att_W, att_b, cW_ih, cW_hh, cb,
        out + 287744,
        biaff_arc_W, (_Float16*)(ws + o_Warc16),
        arc_dep_W, arc_head_W, label_dep_W, label_head_W,
        (_Float16*)(ws + o_Wh16));

    heads_mfma<<<dim3(8, 8, 4), 256, 0, stream>>>(
        (const _Float16*)(ws + o_lstmh), (const _Float16*)(ws + o_Wh16),
        arc_dep_b, arc_head_b, label_dep_b, label_head_b,
        (_Float16*)(ws + o_AD16), (_Float16*)(ws + o_AH16),
        ws + o_LD, (_Float16*)(ws + o_LH16));

    uv2_k<<<512, 128, 0, stream>>>(best_arcs, (const _Float16*)(ws + o_LH16),
                                   ws + o_LD, (_Float16*)(ws + o_Uh), ws + o_V);

    // tail1: gemm1 (64 blocks) || label biaffine (3600 blocks, atomic)
    tail1_k<<<3664, 256, 0, stream>>>(
        (const _Float16*)(ws + o_AH16), (const _Float16*)(ws + o_Warc16),
        (_Float16*)(ws + o_P16),
        (const _Float16*)(ws + o_Uh), (const _Float16*)(ws + o_Bh),
        ws + o_V, ws + o_sel);

    // tail2: gemm2 (64 blocks) || lsm (2 blocks)
    tail2_k<<<66, 256, 0, stream>>>(
        (const _Float16*)(ws + o_P16), (const _Float16*)(ws + o_AD16),
        out, ws + o_sel, out + 262144);

    softmax_rows<<<512, 256, 0, stream>>>(out);
}

// Round 8
// 1249.963 us; speedup vs baseline: 1.1323x; 1.0427x over previous
//
#include <hip/hip_runtime.h>
#include <hip/hip_fp16.h>

// ---------------------------------------------------------------------------
// Problem constants
//   S=512 tokens, WD=300, TD=100, CE=20, CH=20, H=512, LAB=50, MAXW=16
// Outputs: arc_scores (512x512) | label_scores (50x512) | char_embeds (20x512)
//
// Round-8 structure = round-7 (passed, 1303us) with ONE delta:
//   lstm_core gains (a) shfl_xor(32) in-register pre-reduce (tail LDS reads
//   8->4) and (b) exchange-store-before-output-store. These shorten the
//   per-step tail latency segment ahead of the agent-visibility floor.
//   Everything else (fused_k roles, tail1/tail2 merge, layouts) is verbatim r7.
// ---------------------------------------------------------------------------

static __device__ __forceinline__ float sigm(float x) { return 1.f / (1.f + __expf(-x)); }
static __device__ __forceinline__ float ftanh(float x) {
    x = fminf(15.f, fmaxf(-15.f, x));
    float e = __expf(2.f * x);
    return (e - 1.f) / (e + 1.f);
}

typedef _Float16 h2_t __attribute__((ext_vector_type(2)));
typedef _Float16 h8_t __attribute__((ext_vector_type(8)));
typedef float f4_t __attribute__((ext_vector_type(4)));
union U32H2 { unsigned u; h2_t h; unsigned short s[2]; };

static __device__ __forceinline__ float dot2f(unsigned wa, unsigned hb, float c) {
#if __has_builtin(__builtin_amdgcn_fdot2)
    U32H2 a, b; a.u = wa; b.u = hb;
    return __builtin_amdgcn_fdot2(a.h, b.h, c, false);
#else
    U32H2 a, b; a.u = wa; b.u = hb;
    return c + (float)a.h[0] * (float)b.h[0] + (float)a.h[1] * (float)b.h[1];
#endif
}
static __device__ __forceinline__ unsigned short f2h16(float x) {
    return __half_as_ushort(__float2half(x));
}

// ---------------------------------------------------------------------------
// h-queue primitives: agent-scope relaxed atomics. PROVEN (r0/r3/r6/r7).
// sc0/scope-reduction experiments permanently shelved (r1/r2/r4 hang family).
// ---------------------------------------------------------------------------
static __device__ __forceinline__ unsigned long long hq_ld(const unsigned long long* p) {
    return __hip_atomic_load(p, __ATOMIC_RELAXED, __HIP_MEMORY_SCOPE_AGENT);
}
static __device__ __forceinline__ void hq_st(unsigned long long* p, unsigned long long v) {
    __hip_atomic_store(p, v, __ATOMIC_RELAXED, __HIP_MEMORY_SCOPE_AGENT);
}

// ---------------------------------------------------------------------------
// Recurrent biLSTM core — r3/r7 protocol with two tail micro-opts:
//  (a) pre-reduce: lanes l and l^32 of wave w hold dim-groups {2w, 2w+1} for
//      the same gate-slot g=l&31; one shfl_xor(32) sums them in-register, so
//      only lanes with (tid&32)==0 write LDS and the 32-lane tail reads 4
//      partials (waves 0..3) instead of 8.
//  (b) the hq exchange store issues BEFORE the lstmh output store — the
//      exchange is what unblocks the other 15 blocks' polls.
// Exchange protocol (tags, addresses, scopes, memset init) unchanged.
// ---------------------------------------------------------------------------
static __device__ void lstm_core(int dir, int s, int tid,
                                 const float* __restrict__ Whh,
                                 const float* __restrict__ xp,
                                 _Float16* __restrict__ lstmh,
                                 unsigned long long* __restrict__ hq,
                                 float* __restrict__ red /* 2*1024 floats LDS */) {
    int lane = tid & 63;
    int g = tid & 31, p = tid >> 5;

    unsigned Wreg[4][32];
#pragma unroll
    for (int q = 0; q < 4; ++q) {
        int gr = q * 512 + s * 32 + g;
        const float* wrow = Whh + (size_t)gr * 512 + p * 64;
#pragma unroll
        for (int u = 0; u < 32; ++u) {
            unsigned lo = f2h16(wrow[2 * u]);
            unsigned hi = f2h16(wrow[2 * u + 1]);
            Wreg[q][u] = lo | (hi << 16);
        }
    }

    float c = 0.f;
    unsigned long long* hbase = hq + dir * 512;
    int qidx = tid;

    for (int t = 0; t < 512; ++t) {
        float x0 = 0.f, x1 = 0.f, x2 = 0.f, x3 = 0.f;
        if (tid < 32) {
            const float* x = xp + (size_t)t * 2048;
            int col = s * 32 + tid;
            x0 = x[col]; x1 = x[512 + col]; x2 = x[1024 + col]; x3 = x[1536 + col];
        }

        unsigned long long* hin = hbase + (t & 1) * 256;
        unsigned tag = (unsigned)t & 0xffffu;
        unsigned long long v = hq_ld(hin + qidx);
        while ((((unsigned)(v >> 16)) & 0xffffu) != tag || ((unsigned)(v >> 48)) != tag)
            v = hq_ld(hin + qidx);
        unsigned hw = (unsigned)(v & 0xffffu) | (((unsigned)((v >> 32) & 0xffffu)) << 16);

        float a0 = 0.f, a1 = 0.f, a2 = 0.f, a3 = 0.f;
        int half_base = lane & 32;
#pragma unroll
        for (int u = 0; u < 32; ++u) {
            unsigned hwu = (unsigned)__shfl((int)hw, half_base + u);
            a0 = dot2f(Wreg[0][u], hwu, a0);
            a1 = dot2f(Wreg[1][u], hwu, a1);
            a2 = dot2f(Wreg[2][u], hwu, a2);
            a3 = dot2f(Wreg[3][u], hwu, a3);
        }
        // (a) in-register pre-reduce of the wave's two dim-group partials
        a0 += __shfl_xor(a0, 32); a1 += __shfl_xor(a1, 32);
        a2 += __shfl_xor(a2, 32); a3 += __shfl_xor(a3, 32);
        if ((tid & 32) == 0) {
            float* r = red + (t & 1) * 1024 + (tid >> 6) * 128 + g * 4;
            r[0] = a0; r[1] = a1; r[2] = a2; r[3] = a3;
        }
        __syncthreads();

        if (tid < 32) {
            float z0 = 0.f, z1 = 0.f, z2 = 0.f, z3 = 0.f;
            const float* rb = red + (t & 1) * 1024;
#pragma unroll
            for (int pp = 0; pp < 4; ++pp) {
                const float* rr = rb + pp * 128 + tid * 4;
                z0 += rr[0]; z1 += rr[1]; z2 += rr[2]; z3 += rr[3];
            }
            z0 += x0; z1 += x1; z2 += x2; z3 += x3;
            c = sigm(z1) * c + sigm(z0) * ftanh(z2);
            float hn = sigm(z3) * ftanh(c);
            int col = s * 32 + tid;

            // (b) exchange store first — unblocks the other 15 blocks' polls
            unsigned tw = (unsigned)f2h16(hn) | (((unsigned)(t + 1) & 0xffffu) << 16);
            unsigned other = (unsigned)__shfl_down((int)tw, 1);
            if ((tid & 1) == 0) {
                unsigned long long qv = (unsigned long long)tw |
                                        ((unsigned long long)other << 32);
                hq_st(hbase + ((t + 1) & 1) * 256 + (col >> 1), qv);
            }
            int row = dir ? (511 - t) : t;
            lstmh[(size_t)row * 1024 + dir * 512 + col] = (_Float16)hn;
        }
    }
}

// ---------------------------------------------------------------------------
// Shared 64x64 fp16 MFMA GEMM tile body (A[M,K]@B[N,K]^T), used by tail1/tail2.
// ---------------------------------------------------------------------------
typedef _Float16 SRow40[40];
static __device__ void gemm_tile64(const _Float16* __restrict__ A, int lda,
                                   const _Float16* __restrict__ B, int ldb, int K,
                                   _Float16* __restrict__ C16, float* __restrict__ C32,
                                   int m0, int n0, int tid,
                                   SRow40* As, SRow40* Bs) {
    int w = tid >> 6, lane = tid & 63, m = lane & 15, q = lane >> 4;
    int srow = tid >> 2, scol = (tid & 3) * 8;

    f4_t acc[4];
#pragma unroll
    for (int cc = 0; cc < 4; ++cc) acc[cc] = 0;

    for (int k0 = 0; k0 < K; k0 += 32) {
        uint4 ad = *(const uint4*)(A + (size_t)(m0 + srow) * lda + k0 + scol);
        uint4 bd = *(const uint4*)(B + (size_t)(n0 + srow) * ldb + k0 + scol);
        __syncthreads();
        *(uint4*)(&As[srow][scol]) = ad;
        *(uint4*)(&Bs[srow][scol]) = bd;
        __syncthreads();
        h8_t a  = *(const h8_t*)(&As[w * 16 + m][q * 8]);
        h8_t b0 = *(const h8_t*)(&Bs[ 0 + m][q * 8]);
        h8_t b1 = *(const h8_t*)(&Bs[16 + m][q * 8]);
        h8_t b2 = *(const h8_t*)(&Bs[32 + m][q * 8]);
        h8_t b3 = *(const h8_t*)(&Bs[48 + m][q * 8]);
        acc[0] = __builtin_amdgcn_mfma_f32_16x16x32_f16(a, b0, acc[0], 0, 0, 0);
        acc[1] = __builtin_amdgcn_mfma_f32_16x16x32_f16(a, b1, acc[1], 0, 0, 0);
        acc[2] = __builtin_amdgcn_mfma_f32_16x16x32_f16(a, b2, acc[2], 0, 0, 0);
        acc[3] = __builtin_amdgcn_mfma_f32_16x16x32_f16(a, b3, acc[3], 0, 0, 0);
    }
#pragma unroll
    for (int r = 0; r < 4; ++r) {
        int row = m0 + w * 16 + q * 4 + r;
#pragma unroll
        for (int cc = 0; cc < 4; ++cc) {
            int ncol = n0 + cc * 16 + m;
            if (C16) C16[(size_t)row * 512 + ncol] = (_Float16)acc[cc][r];
            else     C32[(size_t)row * 512 + ncol] = acc[cc][r];
        }
    }
}

// ---------------------------------------------------------------------------
// xproj (fp32 tile GEMM) with FUSED embedding gather — r3/r7 verbatim.
// ---------------------------------------------------------------------------
__global__ __launch_bounds__(256) void xproj_k(
    const int* __restrict__ sentence, const int* __restrict__ tags,
    const float* __restrict__ word_emb, const float* __restrict__ tag_emb,
    const float* __restrict__ Wf, const float* __restrict__ bf, float* __restrict__ Cf,
    const float* __restrict__ Wb, const float* __restrict__ bb, float* __restrict__ Cb) {
    __shared__ float smemf[2 * 16 * 65];
    typedef float Row65[65];
    Row65* As = (Row65*)smemf;
    Row65* Bs = (Row65*)(smemf + 16 * 65);
    int idx = blockIdx.x;
    int z = idx >> 8, rem = idx & 255;
    int bn = (rem & 31) * 64, bm = (rem >> 5) * 64;
    const float* W = z ? Wb : Wf;
    const float* bias = z ? bb : bf;
    float* C = z ? Cb : Cf;
    int tx = threadIdx.x & 15, ty = threadIdx.x >> 4;
    float acc[4][4] = {};
    for (int k0 = 0; k0 < 400; k0 += 16) {
#pragma unroll
        for (int i = 0; i < 4; ++i) {
            int e = threadIdx.x + i * 256;
            int m = e >> 4, kk = e & 15;
            int row = bm + m; if (z) row = 511 - row;
            int k = k0 + kk;
            float av = (k < 300) ? word_emb[(size_t)sentence[row] * 300 + k]
                                 : tag_emb[(size_t)tags[row] * 100 + (k - 300)];
            As[kk][m] = av;
            Bs[kk][m] = W[(size_t)(bn + m) * 400 + k];
        }
        __syncthreads();
#pragma unroll
        for (int kk = 0; kk < 16; ++kk) {
            float a0 = As[kk][ty * 4 + 0], a1 = As[kk][ty * 4 + 1];
            float a2 = As[kk][ty * 4 + 2], a3 = As[kk][ty * 4 + 3];
            float b0 = Bs[kk][tx * 4 + 0], b1 = Bs[kk][tx * 4 + 1];
            float b2 = Bs[kk][tx * 4 + 2], b3 = Bs[kk][tx * 4 + 3];
            acc[0][0] += a0 * b0; acc[0][1] += a0 * b1; acc[0][2] += a0 * b2; acc[0][3] += a0 * b3;
            acc[1][0] += a1 * b0; acc[1][1] += a1 * b1; acc[1][2] += a1 * b2; acc[1][3] += a1 * b3;
            acc[2][0] += a2 * b0; acc[2][1] += a2 * b1; acc[2][2] += a2 * b2; acc[2][3] += a2 * b3;
            acc[3][0] += a3 * b0; acc[3][1] += a3 * b1; acc[3][2] += a3 * b2; acc[3][3] += a3 * b3;
        }
        __syncthreads();
    }
#pragma unroll
    for (int i = 0; i < 4; ++i) {
#pragma unroll
        for (int j = 0; j < 4; ++j) {
            int n = bn + tx * 4 + j;
            C[(size_t)(bm + ty * 4 + i) * 2048 + n] = acc[i][j] + bias[n];
        }
    }
}

// ---------------------------------------------------------------------------
// FUSED kernel — r7 role map verbatim:
//   [   0,  32) biLSTM (dir = bid>>4, s = bid&15)
//   [  32, 544) char LSTM + gram attention (512)
//   [ 544,1568) hconv: 4 head weight mats fp32->fp16 (1024)
//   [1568,2080) warc conv fp32[512][513] -> fp16[512][544] (512)
//   [2080,6130) bconv: biaff_label_W -> fp16 [l][k][h] (4050)
// ---------------------------------------------------------------------------
__global__ __launch_bounds__(256) void fused_k(
    const float* __restrict__ W_hh_f, const float* __restrict__ W_hh_b,
    const float* __restrict__ xpf, const float* __restrict__ xpb,
    _Float16* __restrict__ lstmh, unsigned long long* __restrict__ hq,
    const float* __restrict__ BW, _Float16* __restrict__ Bh,
    const int* __restrict__ chars, const int* __restrict__ char_lengths,
    const float* __restrict__ char_emb, const float* __restrict__ att_W,
    const float* __restrict__ att_b, const float* __restrict__ cW_ih,
    const float* __restrict__ cW_hh, const float* __restrict__ cb,
    float* __restrict__ out2,
    const float* __restrict__ Warc, _Float16* __restrict__ W16arc,
    const float* __restrict__ hw0, const float* __restrict__ hw1,
    const float* __restrict__ hw2, const float* __restrict__ hw3,
    _Float16* __restrict__ Wh16) {
    __shared__ __align__(16) unsigned char smem[16384];
    int bid = blockIdx.x;
    int tid = threadIdx.x;

    if (bid < 32) {
        // ---------------- biLSTM ----------------
        int dir = bid >> 4, s = bid & 15;
        const float* Whh = dir ? W_hh_b : W_hh_f;
        const float* xp = dir ? xpb : xpf;
        lstm_core(dir, s, tid, Whh, xp, lstmh, hq, (float*)smem);
    } else if (bid < 544) {
        // ---------------- char LSTM + gram attention ----------------
        float* Wih = (float*)smem;
        float* Whh2 = Wih + 1600;
        float* cbs = Whh2 + 1600;
        float* attsh = cbs + 80;
        float* xsh = attsh + 20;
        float* hsh = xsh + 20;
        float* prodsh = hsh + 20;
        int wd = bid - 32;
        for (int i = tid; i < 1600; i += 256) { Wih[i] = cW_ih[i]; Whh2[i] = cW_hh[i]; }
        for (int i = tid; i < 80; i += 256) cbs[i] = cb[i];
        if (tid < 20) { attsh[tid] = att_W[tid]; hsh[tid] = 0.f; }
        __syncthreads();

        int L = char_lengths[wd];
        float c = 0.f, accj = 0.f;
        for (int t = 0; t < 16; ++t) {
            if (tid < 20) xsh[tid] = char_emb[(size_t)chars[wd * 16 + t] * 20 + tid];
            __syncthreads();
            float hn = 0.f;
            if (tid < 20) {
                float z[4];
#pragma unroll
                for (int q = 0; q < 4; ++q) {
                    int rr = q * 20 + tid;
                    float sacc = cbs[rr];
                    for (int d = 0; d < 20; ++d)
                        sacc += Wih[rr * 20 + d] * xsh[d] + Whh2[rr * 20 + d] * hsh[d];
                    z[q] = sacc;
                }
                c = sigm(z[1]) * c + sigm(z[0]) * ftanh(z[2]);
                hn = sigm(z[3]) * ftanh(c);
            }
            __syncthreads();
            if (tid < 20) { hsh[tid] = hn; prodsh[tid] = hn * attsh[tid]; }
            __syncthreads();
            if (tid < 20 && t < L) {
                float st = 0.f;
                for (int k = 0; k < 20; ++k) st += prodsh[k];
                accj += hn * st;
            }
            __syncthreads();
        }
        if (tid < 20) out2[tid * 512 + wd] = accj + att_b[0];
    } else if (bid < 1568) {
        // ---------------- hconv: 4 head weight matrices fp32 -> fp16 --------
        size_t e0 = ((size_t)(bid - 544) * 256 + tid) * 8;
        int mat = (int)(e0 >> 19);
        size_t off = e0 & 524287;
        const float* src = (mat == 0 ? hw0 : mat == 1 ? hw1 : mat == 2 ? hw2 : hw3) + off;
        float4 f0 = ((const float4*)src)[0];
        float4 f1 = ((const float4*)src)[1];
        __align__(16) _Float16 hv[8];
        hv[0] = (_Float16)f0.x; hv[1] = (_Float16)f0.y;
        hv[2] = (_Float16)f0.z; hv[3] = (_Float16)f0.w;
        hv[4] = (_Float16)f1.x; hv[5] = (_Float16)f1.y;
        hv[6] = (_Float16)f1.z; hv[7] = (_Float16)f1.w;
        *(uint4*)(Wh16 + e0) = *(const uint4*)hv;
    } else if (bid < 2080) {
        // ---------------- warc conv: [512][513] fp32 -> [512][544] fp16 -----
        int t = bid - 1568;
        for (int j = tid; j < 544; j += 256)
            W16arc[(size_t)t * 544 + j] = (_Float16)((j < 513) ? Warc[(size_t)t * 513 + j] : 0.f);
    } else {
        // ---------------- bconv ----------------
        typedef _Float16 TsRow[68];
        TsRow* Ts = (TsRow*)smem;
        int b2 = bid - 2080;
        int lb = b2 / 81, rem = b2 % 81;
        int h0 = (rem % 9) * 64, k0 = (rem / 9) * 64;
        const float* Bl = BW + (size_t)lb * 513 * 513;
        _Float16* BhL = Bh + (size_t)lb * 576 * 544;
        int tr = tid >> 4, tc = tid & 15;
#pragma unroll
        for (int i = 0; i < 4; ++i) {
            int hl = tr + i * 16;
            int h = h0 + hl;
#pragma unroll
            for (int j = 0; j < 4; ++j) {
                int k = k0 + tc * 4 + j;
                float v = (h < 513 && k < 513) ? Bl[(size_t)h * 513 + k] : 0.f;
                Ts[hl][tc * 4 + j] = (_Float16)v;
            }
        }
        __syncthreads();
        int cr = tid >> 2, hb = (tid & 3) * 16;
        int hg = h0 + hb;
        if (hg < 544) {
            __align__(16) _Float16 tmp[16];
#pragma unroll
            for (int j = 0; j < 16; ++j) tmp[j] = Ts[hb + j][cr];
            uint4* dst = (uint4*)(BhL + (size_t)(k0 + cr) * 544 + hg);
            dst[0] = ((const uint4*)tmp)[0];
            dst[1] = ((const uint4*)tmp)[1];
        }
    }
}

// ---------------------------------------------------------------------------
// Heads MFMA — r3/r7 verbatim.
// ---------------------------------------------------------------------------
__global__ __launch_bounds__(256) void heads_mfma(
    const _Float16* __restrict__ A, const _Float16* __restrict__ Wh,
    const float* __restrict__ b0, const float* __restrict__ b1,
    const float* __restrict__ b2, const float* __restrict__ b3,
    _Float16* __restrict__ AD16, _Float16* __restrict__ AH16,
    float* __restrict__ LD, _Float16* __restrict__ LH16) {
    __shared__ _Float16 As[64][40];
    __shared__ _Float16 Bs[64][40];
    int hd = blockIdx.z;
    int m0 = blockIdx.y * 64, n0 = blockIdx.x * 64;
    const _Float16* Bp = Wh + (size_t)hd * 512 * 1024;
    const float* bias = (hd == 0) ? b0 : (hd == 1) ? b1 : (hd == 2) ? b2 : b3;
    int tid = threadIdx.x;
    int w = tid >> 6, lane = tid & 63, m = lane & 15, q = lane >> 4;
    int srow = tid >> 2, scol = (tid & 3) * 8;

    f4_t acc[4];
#pragma unroll
    for (int cc = 0; cc < 4; ++cc) acc[cc] = 0;

    for (int k0 = 0; k0 < 1024; k0 += 32) {
        uint4 ad = *(const uint4*)(A + (size_t)(m0 + srow) * 1024 + k0 + scol);
        uint4 bd = *(const uint4*)(Bp + (size_t)(n0 + srow) * 1024 + k0 + scol);
        __syncthreads();
        *(uint4*)(&As[srow][scol]) = ad;
        *(uint4*)(&Bs[srow][scol]) = bd;
        __syncthreads();
        h8_t a  = *(const h8_t*)(&As[w * 16 + m][q * 8]);
        h8_t bb0 = *(const h8_t*)(&Bs[ 0 + m][q * 8]);
        h8_t bb1 = *(const h8_t*)(&Bs[16 + m][q * 8]);
        h8_t bb2 = *(const h8_t*)(&Bs[32 + m][q * 8]);
        h8_t bb3 = *(const h8_t*)(&Bs[48 + m][q * 8]);
        acc[0] = __builtin_amdgcn_mfma_f32_16x16x32_f16(a, bb0, acc[0], 0, 0, 0);
        acc[1] = __builtin_amdgcn_mfma_f32_16x16x32_f16(a, bb1, acc[1], 0, 0, 0);
        acc[2] = __builtin_amdgcn_mfma_f32_16x16x32_f16(a, bb2, acc[2], 0, 0, 0);
        acc[3] = __builtin_amdgcn_mfma_f32_16x16x32_f16(a, bb3, acc[3], 0, 0, 0);
    }
#pragma unroll
    for (int r = 0; r < 4; ++r) {
        int row = m0 + w * 16 + q * 4 + r;
#pragma unroll
        for (int cc = 0; cc < 4; ++cc) {
            int ncol = n0 + cc * 16 + m;
            float v = fmaxf(acc[cc][r] + bias[ncol], 0.f);
            if (hd == 2)      LD[(size_t)row * 512 + ncol] = v;
            else if (hd == 0) AD16[(size_t)row * 512 + ncol] = (_Float16)v;
            else {
                _Float16* dst = (hd == 1) ? AH16 : LH16;
                dst[(size_t)row * 544 + ncol] = (_Float16)v;
            }
        }
    }
    // ones + zero-pad columns (512..543) for the 544-stride fp16 heads
    if ((hd == 1 || hd == 3) && blockIdx.x == 7 && tid < 64) {
        _Float16* dst = (hd == 1) ? AH16 : LH16;
        int row = m0 + tid;
        dst[(size_t)row * 544 + 512] = (_Float16)1.f;
        for (int j = 513; j < 544; ++j) dst[(size_t)row * 544 + j] = (_Float16)0.f;
    }
}

// ---------------------------------------------------------------------------
// uv2: Uh[t] = LH16[best_arcs[t]] (fp16 row copy, 544), V[t] = [LD[t],1,pad0]
// ---------------------------------------------------------------------------
__global__ void uv2_k(const int* __restrict__ best_arcs,
                      const _Float16* __restrict__ LH16, const float* __restrict__ LD,
                      _Float16* __restrict__ Uh, float* __restrict__ V) {
    int t = blockIdx.x;
    int ba = best_arcs[t];
    const unsigned* src = (const unsigned*)(LH16 + (size_t)ba * 544);
    unsigned* dst = (unsigned*)(Uh + (size_t)t * 544);
    for (int j = threadIdx.x; j < 272; j += blockDim.x) dst[j] = src[j];
    for (int j = threadIdx.x; j < 516; j += blockDim.x)
        V[t * 516 + j] = (j < 512) ? LD[(size_t)t * 512 + j] : (j == 512 ? 1.f : 0.f);
}

// ---------------------------------------------------------------------------
// tail1: blocks [0,64) = gemm1 (P16 = AH16 @ Warc16^T, K=544, fp16 out);
//        blocks [64,3664) = label biaffine (r3 atomic 3600-block form).
// ---------------------------------------------------------------------------
__global__ __launch_bounds__(256) void tail1_k(
    const _Float16* __restrict__ AH16, const _Float16* __restrict__ Warc16,
    _Float16* __restrict__ P16,
    const _Float16* __restrict__ Uh, const _Float16* __restrict__ Bh,
    const float* __restrict__ V, float* __restrict__ sel) {
    __shared__ _Float16 As[64][40];
    __shared__ _Float16 Bs[64][40];
    int bid = blockIdx.x;
    int tid = threadIdx.x;

    if (bid < 64) {
        gemm_tile64(AH16, 544, Warc16, 544, 544, P16, nullptr,
                    (bid >> 3) * 64, (bid & 7) * 64, tid, (SRow40*)As, (SRow40*)Bs);
        return;
    }

    // ---------------- label biaffine (r3 atomic body) ----------------
    int b2 = bid - 64;
    int kx = b2 % 9, ty2 = (b2 / 9) % 8, l = b2 / 72;
    int t0 = ty2 * 64, k0 = kx * 64;
    int w = tid >> 6, lane = tid & 63, m = lane & 15, q = lane >> 4;
    const _Float16* Bl = Bh + (size_t)l * 576 * 544;
    int srow = tid >> 2, scol = (tid & 3) * 8;

    f4_t acc[4];
#pragma unroll
    for (int c = 0; c < 4; ++c) acc[c] = 0;

    for (int h0 = 0; h0 < 544; h0 += 32) {
        uint4 ud = *(const uint4*)(Uh + (size_t)(t0 + srow) * 544 + h0 + scol);
        uint4 bd = *(const uint4*)(Bl + (size_t)(k0 + srow) * 544 + h0 + scol);
        __syncthreads();
        *(uint4*)(&As[srow][scol]) = ud;
        *(uint4*)(&Bs[srow][scol]) = bd;
        __syncthreads();
        h8_t a  = *(const h8_t*)(&As[w * 16 + m][q * 8]);
        h8_t b0 = *(const h8_t*)(&Bs[ 0 + m][q * 8]);
        h8_t b1 = *(const h8_t*)(&Bs[16 + m][q * 8]);
        h8_t b2v = *(const h8_t*)(&Bs[32 + m][q * 8]);
        h8_t b3 = *(const h8_t*)(&Bs[48 + m][q * 8]);
        acc[0] = __builtin_amdgcn_mfma_f32_16x16x32_f16(a, b0, acc[0], 0, 0, 0);
        acc[1] = __builtin_amdgcn_mfma_f32_16x16x32_f16(a, b1, acc[1], 0, 0, 0);
        acc[2] = __builtin_amdgcn_mfma_f32_16x16x32_f16(a, b2v, acc[2], 0, 0, 0);
        acc[3] = __builtin_amdgcn_mfma_f32_16x16x32_f16(a, b3, acc[3], 0, 0, 0);
    }

    float* selp = sel + (size_t)l * 512;
#pragma unroll
    for (int r = 0; r < 4; ++r) {
        int t = t0 + w * 16 + q * 4 + r;
        float vsum = 0.f;
#pragma unroll
        for (int c = 0; c < 4; ++c) {
            int k = k0 + c * 16 + m;
            float vv = (k < 513) ? V[(size_t)t * 516 + k] : 0.f;
            vsum += acc[c][r] * vv;
        }
#pragma unroll
        for (int off = 1; off < 16; off <<= 1)
            vsum += __shfl_xor(vsum, off);
        if (m == 0) atomicAdd(selp + t, vsum);
    }
}

// ---------------------------------------------------------------------------
// tail2: blocks [0,64) = gemm2 (S = P16 @ AD16^T, K=512, fp32 out -> out);
//        blocks [64,66) = lsm (log_softmax over l for each t).
// ---------------------------------------------------------------------------
__global__ __launch_bounds__(256) void tail2_k(
    const _Float16* __restrict__ P16, const _Float16* __restrict__ AD16,
    float* __restrict__ Smat,
    const float* __restrict__ sel, float* __restrict__ out1) {
    __shared__ _Float16 As[64][40];
    __shared__ _Float16 Bs[64][40];
    int bid = blockIdx.x;
    int tid = threadIdx.x;

    if (bid < 64) {
        gemm_tile64(P16, 512, AD16, 512, 512, nullptr, Smat,
                    (bid >> 3) * 64, (bid & 7) * 64, tid, (SRow40*)As, (SRow40*)Bs);
        return;
    }
    int t = (bid - 64) * 256 + tid;
    if (t >= 512) return;
    float m = -1e30f;
    for (int l = 0; l < 50; ++l) m = fmaxf(m, sel[l * 512 + t]);
    float ssum = 0.f;
    for (int l = 0; l < 50; ++l) ssum += __expf(sel[l * 512 + t] - m);
    float lse = m + __logf(ssum);
    for (int l = 0; l < 50; ++l) out1[l * 512 + t] = sel[l * 512 + t] - lse;
}

// ---------------------------------------------------------------------------
// Row softmax in place (512x512) — runs last (arc region only).
// ---------------------------------------------------------------------------
__global__ __launch_bounds__(256) void softmax_rows(float* __restrict__ Smat) {
    __shared__ float sdata[256];
    int i = blockIdx.x, tid = threadIdx.x;
    float* row = Smat + (size_t)i * 512;
    float m = -1e30f;
    for (int j = tid; j < 512; j += 256) m = fmaxf(m, row[j]);
    sdata[tid] = m; __syncthreads();
    for (int off = 128; off > 0; off >>= 1) {
        if (tid < off) sdata[tid] = fmaxf(sdata[tid], sdata[tid + off]);
        __syncthreads();
    }
    m = sdata[0]; __syncthreads();
    float ssum = 0.f;
    for (int j = tid; j < 512; j += 256) { float e = __expf(row[j] - m); row[j] = e; ssum += e; }
    sdata[tid] = ssum; __syncthreads();
    for (int off = 128; off > 0; off >>= 1) {
        if (tid < off) sdata[tid] += sdata[tid + off];
        __syncthreads();
    }
    float inv = 1.f / sdata[0];
    for (int j = tid; j < 512; j += 256) row[j] *= inv;
}

// ---------------------------------------------------------------------------
extern "C" void kernel_launch(void* const* d_in, const int* in_sizes, int n_in,
                              void* d_out, int out_size, void* d_ws, size_t ws_size,
                              hipStream_t stream) {
    const int* sentence     = (const int*)d_in[0];
    const int* tags         = (const int*)d_in[1];
    const int* chars        = (const int*)d_in[2];
    const int* char_lengths = (const int*)d_in[3];
    const int* best_arcs    = (const int*)d_in[4];
    const float* word_emb   = (const float*)d_in[5];
    const float* tag_emb    = (const float*)d_in[6];
    const float* char_emb   = (const float*)d_in[7];
    const float* att_W      = (const float*)d_in[8];
    const float* att_b      = (const float*)d_in[9];
    const float* W_ih_f     = (const float*)d_in[10];
    const float* W_hh_f     = (const float*)d_in[11];
    const float* b_f        = (const float*)d_in[12];
    const float* W_ih_b     = (const float*)d_in[13];
    const float* W_hh_b     = (const float*)d_in[14];
    const float* b_b        = (const float*)d_in[15];
    const float* cW_ih      = (const float*)d_in[16];
    const float* cW_hh      = (const float*)d_in[17];
    const float* cb         = (const float*)d_in[18];
    const float* arc_dep_W  = (const float*)d_in[19];
    const float* arc_dep_b  = (const float*)d_in[20];
    const float* arc_head_W = (const float*)d_in[21];
    const float* arc_head_b = (const float*)d_in[22];
    const float* label_dep_W  = (const float*)d_in[23];
    const float* label_dep_b  = (const float*)d_in[24];
    const float* label_head_W = (const float*)d_in[25];
    const float* label_head_b = (const float*)d_in[26];
    const float* biaff_arc_W   = (const float*)d_in[27];
    const float* biaff_label_W = (const float*)d_in[28];

    float* ws = (float*)d_ws;
    float* out = (float*)d_out;

    // workspace layout (float offsets) — round-3 proven layout.
    const size_t o_Wh16   = 0;            // 1048576 (fp16 4x512x1024)
    const size_t o_V      = 204800;       // 264192 (born after heads_mfma)
    const size_t o_Uh     = 468992;       // 139264 (fp16 512x544)
    const size_t o_xf     = 1134592;      // 1048576
    const size_t o_xb     = 2183168;      // 1048576
    const size_t o_lstmh  = 3231744;      // 262144 (fp16 512x1024)
    const size_t o_heads  = 3493888;      // 1048576 region, sub-layout:
    const size_t o_LD     = o_heads + 0;       // fp32 512x512   (262144)
    const size_t o_AD16   = o_heads + 262144;  // fp16 512x512   (131072)
    const size_t o_AH16   = o_heads + 393216;  // fp16 512x544   (139264)
    const size_t o_LH16   = o_heads + 532480;  // fp16 512x544   (139264)
    const size_t o_P16    = o_heads + 671744;  // fp16 512x512   (131072)
    const size_t o_Warc16 = o_heads + 802816;  // fp16 512x544   (139264) -> ends 942080
    const size_t o_sel    = 4542464;      // 25600
    const size_t o_hG     = 4568064;      // 2048 (1024 qwords)
    const size_t o_Bh     = 4570112;      // 7833600 (fp16 50x576x544) -> ends 12403712

    hipMemsetAsync(ws + o_hG, 0, 8192, stream);
    hipMemsetAsync(ws + o_sel, 0, 25600 * sizeof(float), stream);

    // input projections (with fused embedding gather) — the LSTM's only prereq
    xproj_k<<<512, 256, 0, stream>>>(sentence, tags, word_emb, tag_emb,
                                     W_ih_f, b_f, ws + o_xf,
                                     W_ih_b, b_b, ws + o_xb);

    // biLSTM (agent-scope exchange + tail micro-opts) + lstm-independent prep
    fused_k<<<6130, 256, 0, stream>>>(
        W_hh_f, W_hh_b, ws + o_xf, ws + o_xb,
        (_Float16*)(ws + o_lstmh), (unsigned long long*)(ws + o_hG),
        biaff_label_W, (_Float16*)(ws + o_Bh),
        chars, char_lengths, char_emb, att_W, att_b, cW_ih, cW_hh, cb,
        out + 287744,
        biaff_arc_W, (_Float16*)(ws + o_Warc16),
        arc_dep_W, arc_head_W, label_dep_W, label_head_W,
        (_Float16*)(ws + o_Wh16));

    heads_mfma<<<dim3(8, 8, 4), 256, 0, stream>>>(
        (const _Float16*)(ws + o_lstmh), (const _Float16*)(ws + o_Wh16),
        arc_dep_b, arc_head_b, label_dep_b, label_head_b,
        (_Float16*)(ws + o_AD16), (_Float16*)(ws + o_AH16),
        ws + o_LD, (_Float16*)(ws + o_LH16));

    uv2_k<<<512, 128, 0, stream>>>(best_arcs, (const _Float16*)(ws + o_LH16),
                                   ws + o_LD, (_Float16*)(ws + o_Uh), ws + o_V);

    // tail1: gemm1 (64 blocks) || label biaffine (3600 blocks, atomic)
    tail1_k<<<3664, 256, 0, stream>>>(
        (const _Float16*)(ws + o_AH16), (const _Float16*)(ws + o_Warc16),
        (_Float16*)(ws + o_P16),
        (const _Float16*)(ws + o_Uh), (const _Float16*)(ws + o_Bh),
        ws + o_V, ws + o_sel);

    // tail2: gemm2 (64 blocks) || lsm (2 blocks)
    tail2_k<<<66, 256, 0, stream>>>(
        (const _Float16*)(ws + o_P16), (const _Float16*)(ws + o_AD16),
        out, ws + o_sel, out + 262144);

    softmax_rows<<<512, 256, 0, stream>>>(out);
}